// Round 1
// 590.586 us; speedup vs baseline: 1.2831x; 1.2831x over previous
//
#include <hip/hip_runtime.h>

typedef unsigned short u16;
typedef __bf16 bf16x8 __attribute__((ext_vector_type(8)));
typedef u16 us8 __attribute__((ext_vector_type(8)));
typedef u16 us4 __attribute__((ext_vector_type(4)));
typedef float floatx4 __attribute__((ext_vector_type(4)));
typedef float f32x4 __attribute__((ext_vector_type(4)));

__device__ inline float b2f(u16 u) {
  union { unsigned u; float f; } x; x.u = ((unsigned)u) << 16; return x.f;
}
__device__ inline u16 f2b(float f) {
  union { float f; unsigned u; } x; x.f = f;
  unsigned r = x.u + 0x7fffu + ((x.u >> 16) & 1u);
  return (u16)(r >> 16);
}

// Probe first 4096 u16 words of x. bf16 data: max|v| ~ 5.7. fp32 data read
// as bf16: low mantissa halves are ~uniform u16 -> |v|>1000 w.p. ~0.46 each.
// force >= 0 overrides (small-ws fallback).
__global__ __launch_bounds__(256)
void detect_dtype(const u16* __restrict__ x, int* __restrict__ flag, int force) {
  __shared__ float sm[4];
  const int t = threadIdx.x;
  float m = 0.f;
  for (int i = t; i < 4096; i += 256) {
    float v = fabsf(b2f(x[i]));
    if (v > m) m = v;  // NaN compares false -> skipped; inf caught
  }
#pragma unroll
  for (int o = 32; o; o >>= 1) m = fmaxf(m, __shfl_xor(m, o, 64));
  if ((t & 63) == 0) sm[t >> 6] = m;
  __syncthreads();
  if (t == 0) {
    float mm = fmaxf(fmaxf(sm[0], sm[1]), fmaxf(sm[2], sm[3]));
    *flag = (force >= 0) ? force : (mm > 1000.0f ? 1 : 0);
  }
}

// Canonicalize an input to bf16: copy (bf16 in) or downconvert (fp32 in).
__global__ __launch_bounds__(256)
void convert_bf16(const void* __restrict__ in, u16* __restrict__ out, long n,
                  const int* __restrict__ flag) {
  const long i = (blockIdx.x * 256L + threadIdx.x) * 8;
  if (i >= n) return;
  if (*flag) {
    const float* p = (const float*)in + i;
    f32x4 a = ((const f32x4*)p)[0];
    f32x4 b = ((const f32x4*)p)[1];
    us8 o;
#pragma unroll
    for (int j = 0; j < 4; j++) { o[j] = f2b(a[j]); o[j + 4] = f2b(b[j]); }
    *(us8*)(out + i) = o;
  } else {
    *(us8*)(out + i) = *((const us8*)in + (i >> 3));
  }
}

// D[M][N] = A[M][K] . B[N][K]^T ; A,B K-contiguous (NT). 128x128 tile,
// 4 waves of 64x64, mfma_f32_16x16x32_bf16, fp32 accum.
// LDS XOR swizzle: 16B slot s at row r stored at slot s^((r>>1)&3).
// Quarter-wave then covers all 8 bank-groups 2x -> 2-way (free) vs 8-way.
template <typename OutT>
__global__ __launch_bounds__(256)
void gemm_nt(const u16* __restrict__ A, long sA, int lda,
             const u16* __restrict__ B, long sB, int ldb,
             OutT* __restrict__ D, long sD, int ldd, int K) {
  __shared__ __align__(16) u16 As[128 * 32];
  __shared__ __align__(16) u16 Bs[128 * 32];
  const int bz = blockIdx.z;
  const u16* Ab = A + (long)bz * sA;
  const u16* Bb = B + (long)bz * sB;
  OutT* Db = D + (long)bz * sD;
  const int tid  = threadIdx.x;
  const int lane = tid & 63;
  const int wave = tid >> 6;
  const int wm = (wave >> 1) * 64, wn = (wave & 1) * 64;
  const int m0 = blockIdx.y * 128, n0 = blockIdx.x * 128;
  const int srow = tid >> 2;
  const int ss   = tid & 3;                       // 16B slot (global side)
  const int sw   = (ss ^ ((srow >> 1) & 3)) * 8;  // swizzled LDS slot (elems)
  const int lr = lane & 15;
  const int rsw = (((lane >> 4) ^ ((lr >> 1) & 3)) * 8);  // swizzled read slot

  floatx4 acc[4][4];
#pragma unroll
  for (int i = 0; i < 4; i++)
#pragma unroll
    for (int j = 0; j < 4; j++) acc[i][j] = (floatx4){0.f, 0.f, 0.f, 0.f};

  for (int k0 = 0; k0 < K; k0 += 32) {
    __syncthreads();
    *(bf16x8*)&As[srow * 32 + sw] =
        *(const bf16x8*)&Ab[(long)(m0 + srow) * lda + k0 + ss * 8];
    *(bf16x8*)&As[(srow + 64) * 32 + sw] =
        *(const bf16x8*)&Ab[(long)(m0 + srow + 64) * lda + k0 + ss * 8];
    *(bf16x8*)&Bs[srow * 32 + sw] =
        *(const bf16x8*)&Bb[(long)(n0 + srow) * ldb + k0 + ss * 8];
    *(bf16x8*)&Bs[(srow + 64) * 32 + sw] =
        *(const bf16x8*)&Bb[(long)(n0 + srow + 64) * ldb + k0 + ss * 8];
    __syncthreads();
    bf16x8 af[4], bfr[4];
#pragma unroll
    for (int i = 0; i < 4; i++)
      af[i] = *(bf16x8*)&As[(wm + i * 16 + lr) * 32 + rsw];
#pragma unroll
    for (int i = 0; i < 4; i++)
      bfr[i] = *(bf16x8*)&Bs[(wn + i * 16 + lr) * 32 + rsw];
#pragma unroll
    for (int mi = 0; mi < 4; mi++)
#pragma unroll
      for (int ni = 0; ni < 4; ni++)
        acc[mi][ni] = __builtin_amdgcn_mfma_f32_16x16x32_bf16(
            af[mi], bfr[ni], acc[mi][ni], 0, 0, 0);
  }

  // C/D layout (m89-verified): col = lane&15, row = (lane>>4)*4 + reg
  const int lc  = lane & 15;
  const int lr4 = (lane >> 4) * 4;
#pragma unroll
  for (int mi = 0; mi < 4; mi++) {
#pragma unroll
    for (int r = 0; r < 4; r++) {
      int gm = m0 + wm + mi * 16 + lr4 + r;
#pragma unroll
      for (int ni = 0; ni < 4; ni++) {
        int gn = n0 + wn + ni * 16 + lc;
        float v = acc[mi][ni][r];
        if constexpr (sizeof(OutT) == 4) Db[(long)gm * ldd + gn] = v;
        else                             Db[(long)gm * ldd + gn] = f2b(v);
      }
    }
  }
}

// ---- split-K symmetric XX^T --------------------------------------------
// G[b] = X X^T is symmetric: compute only the 10 lower-triangle 128x128
// tiles, split K=9216 into 8 chunks of 1152 for occupancy (640 blocks).
// fp32 partials P[(sp*8+bz)*10+t][128][128]; reduce sums+mirrors.
__device__ inline void tile_decode(int t, int& by, int& bx) {
  by = (int)((sqrtf((float)(8 * t + 1)) - 1.0f) * 0.5f);
  bx = t - (by * (by + 1)) / 2;
}

__global__ __launch_bounds__(256)
void gemm_xxt_splitk(const u16* __restrict__ X, float* __restrict__ P) {
  __shared__ __align__(16) u16 As[128 * 32];
  __shared__ __align__(16) u16 Bs[128 * 32];
  const int t  = blockIdx.x;        // 0..9
  const int bz = blockIdx.z >> 3;   // batch
  const int sp = blockIdx.z & 7;    // k-split
  int by, bx;
  tile_decode(t, by, bx);
  const int m0 = by * 128, n0 = bx * 128;
  const u16* Xb = X + (long)bz * 512 * 9216;
  const int tid  = threadIdx.x;
  const int lane = tid & 63;
  const int wave = tid >> 6;
  const int wm = (wave >> 1) * 64, wn = (wave & 1) * 64;
  const int srow = tid >> 2;
  const int ss   = tid & 3;
  const int sw   = (ss ^ ((srow >> 1) & 3)) * 8;
  const int lr = lane & 15;
  const int rsw = (((lane >> 4) ^ ((lr >> 1) & 3)) * 8);

  floatx4 acc[4][4];
#pragma unroll
  for (int i = 0; i < 4; i++)
#pragma unroll
    for (int j = 0; j < 4; j++) acc[i][j] = (floatx4){0.f, 0.f, 0.f, 0.f};

  const int k0beg = sp * 1152;
  for (int k0 = k0beg; k0 < k0beg + 1152; k0 += 32) {
    __syncthreads();
    *(bf16x8*)&As[srow * 32 + sw] =
        *(const bf16x8*)&Xb[(long)(m0 + srow) * 9216 + k0 + ss * 8];
    *(bf16x8*)&As[(srow + 64) * 32 + sw] =
        *(const bf16x8*)&Xb[(long)(m0 + srow + 64) * 9216 + k0 + ss * 8];
    *(bf16x8*)&Bs[srow * 32 + sw] =
        *(const bf16x8*)&Xb[(long)(n0 + srow) * 9216 + k0 + ss * 8];
    *(bf16x8*)&Bs[(srow + 64) * 32 + sw] =
        *(const bf16x8*)&Xb[(long)(n0 + srow + 64) * 9216 + k0 + ss * 8];
    __syncthreads();
    bf16x8 af[4], bfr[4];
#pragma unroll
    for (int i = 0; i < 4; i++)
      af[i] = *(bf16x8*)&As[(wm + i * 16 + lr) * 32 + rsw];
#pragma unroll
    for (int i = 0; i < 4; i++)
      bfr[i] = *(bf16x8*)&Bs[(wn + i * 16 + lr) * 32 + rsw];
#pragma unroll
    for (int mi = 0; mi < 4; mi++)
#pragma unroll
      for (int ni = 0; ni < 4; ni++)
        acc[mi][ni] = __builtin_amdgcn_mfma_f32_16x16x32_bf16(
            af[mi], bfr[ni], acc[mi][ni], 0, 0, 0);
  }

  float* Pb = P + ((long)(sp * 8 + bz) * 10 + t) * 16384;
  const int lc  = lane & 15;
  const int lr4 = (lane >> 4) * 4;
#pragma unroll
  for (int mi = 0; mi < 4; mi++)
#pragma unroll
    for (int r = 0; r < 4; r++) {
      int gm = wm + mi * 16 + lr4 + r;
#pragma unroll
      for (int ni = 0; ni < 4; ni++)
        Pb[gm * 128 + wn + ni * 16 + lc] = acc[mi][ni][r];
    }
}

// Sum the 8 split partials of tile t (batch bz), convert to bf16, write the
// tile and (for off-diagonal tiles) its mirror via an LDS transpose.
__global__ __launch_bounds__(256)
void reduce_xxt(const float* __restrict__ P, u16* __restrict__ G) {
  __shared__ u16 tl[128][130];
  const int t = blockIdx.x, bz = blockIdx.y;
  int by, bx;
  tile_decode(t, by, bx);
  const int m0 = by * 128, n0 = bx * 128;
  u16* Gb = G + (long)bz * 512 * 512;
  for (int e = threadIdx.x; e < 4096; e += 256) {
    const int idx = e * 4;
    const int m = idx >> 7, n = idx & 127;
    f32x4 s = {0.f, 0.f, 0.f, 0.f};
#pragma unroll
    for (int sp = 0; sp < 8; sp++) {
      f32x4 v = *(const f32x4*)&P[(((long)sp * 8 + bz) * 10 + t) * 16384 + idx];
      s.x += v.x; s.y += v.y; s.z += v.z; s.w += v.w;
    }
    us4 o = {f2b(s.x), f2b(s.y), f2b(s.z), f2b(s.w)};
    *(us4*)&Gb[(long)(m0 + m) * 512 + n0 + n] = o;
    tl[m][n] = o[0]; tl[m][n + 1] = o[1]; tl[m][n + 2] = o[2]; tl[m][n + 3] = o[3];
  }
  if (m0 == n0) return;
  __syncthreads();
  for (int e = threadIdx.x; e < 4096; e += 256) {
    const int idx = e * 4;
    const int nr = idx >> 7, mc = idx & 127;
    us4 o = {tl[mc][nr], tl[mc + 1][nr], tl[mc + 2][nr], tl[mc + 3][nr]};
    *(us4*)&Gb[(long)(n0 + nr) * 512 + m0 + mc] = o;
  }
}

// out[b][o][n] = sum_c M[b][o][c] * X[b][c][n] + bias[b][o]  (NN GEMM)
// Output dtype chosen by *flag (1 -> fp32, 0 -> bf16).
__global__ __launch_bounds__(256)
void gemm_nn_out(const u16* __restrict__ A, const u16* __restrict__ B,
                 const float* __restrict__ bias, void* __restrict__ Dout,
                 const int* __restrict__ flag) {
  __shared__ __align__(16) u16 As[128 * 32];
  __shared__ __align__(16) u16 Bs[128 * 40];  // [n][k], k padded to 40
  const int f = *flag;
  const int bz = blockIdx.z;
  const u16* Ab = A + (long)bz * 512 * 512;
  const u16* Bb = B + (long)bz * 512 * 9216;
  const float* cb = bias + bz * 512;
  const int tid  = threadIdx.x;
  const int lane = tid & 63;
  const int wave = tid >> 6;
  const int wm = (wave >> 1) * 64, wn = (wave & 1) * 64;
  const int m0 = blockIdx.y * 128, n0 = blockIdx.x * 128;
  const int srow = tid >> 2;
  const int ss   = tid & 3;
  const int sw   = (ss ^ ((srow >> 1) & 3)) * 8;
  const int kk = tid >> 3;          // 0..31
  const int nn = (tid & 7) * 16;    // 0..112
  const int lr = lane & 15;
  const int lk = (lane >> 4) * 8;
  const int rsw = (((lane >> 4) ^ ((lr >> 1) & 3)) * 8);

  floatx4 acc[4][4];
#pragma unroll
  for (int i = 0; i < 4; i++)
#pragma unroll
    for (int j = 0; j < 4; j++) acc[i][j] = (floatx4){0.f, 0.f, 0.f, 0.f};

  for (int k0 = 0; k0 < 512; k0 += 32) {
    __syncthreads();
    *(bf16x8*)&As[srow * 32 + sw] =
        *(const bf16x8*)&Ab[(long)(m0 + srow) * 512 + k0 + ss * 8];
    *(bf16x8*)&As[(srow + 64) * 32 + sw] =
        *(const bf16x8*)&Ab[(long)(m0 + srow + 64) * 512 + k0 + ss * 8];
    us8 v0 = *(const us8*)&Bb[(long)(k0 + kk) * 9216 + n0 + nn];
    us8 v1 = *(const us8*)&Bb[(long)(k0 + kk) * 9216 + n0 + nn + 8];
#pragma unroll
    for (int j = 0; j < 8; j++) {
      Bs[(nn + j) * 40 + kk]     = v0[j];
      Bs[(nn + 8 + j) * 40 + kk] = v1[j];
    }
    __syncthreads();
    bf16x8 af[4], bfr[4];
#pragma unroll
    for (int i = 0; i < 4; i++)
      af[i] = *(bf16x8*)&As[(wm + i * 16 + lr) * 32 + rsw];
#pragma unroll
    for (int i = 0; i < 4; i++)
      bfr[i] = *(bf16x8*)&Bs[(wn + i * 16 + lr) * 40 + lk];
#pragma unroll
    for (int mi = 0; mi < 4; mi++)
#pragma unroll
      for (int ni = 0; ni < 4; ni++)
        acc[mi][ni] = __builtin_amdgcn_mfma_f32_16x16x32_bf16(
            af[mi], bfr[ni], acc[mi][ni], 0, 0, 0);
  }

  const int lc  = lane & 15;
  const int lr4 = (lane >> 4) * 4;
  if (f) {
    float* Db = (float*)Dout + (long)bz * 512 * 9216;
#pragma unroll
    for (int mi = 0; mi < 4; mi++)
#pragma unroll
      for (int r = 0; r < 4; r++) {
        int gm = m0 + wm + mi * 16 + lr4 + r;
        float bv = cb[gm];
#pragma unroll
        for (int ni = 0; ni < 4; ni++)
          Db[(long)gm * 9216 + n0 + wn + ni * 16 + lc] = acc[mi][ni][r] + bv;
      }
  } else {
    u16* Db = (u16*)Dout + (long)bz * 512 * 9216;
#pragma unroll
    for (int mi = 0; mi < 4; mi++)
#pragma unroll
      for (int r = 0; r < 4; r++) {
        int gm = m0 + wm + mi * 16 + lr4 + r;
        float bv = cb[gm];
#pragma unroll
        for (int ni = 0; ni < 4; ni++)
          Db[(long)gm * 9216 + n0 + wn + ni * 16 + lc] = f2b(acc[mi][ni][r] + bv);
      }
  }
}

// r[b][c] = sum_n x[b][c][n]. One wave per row.
__global__ __launch_bounds__(256)
void rowsum(const u16* __restrict__ x, float* __restrict__ r) {
  const int row  = blockIdx.x * 4 + (threadIdx.x >> 6);
  const int lane = threadIdx.x & 63;
  const u16* p = x + (long)row * 9216;
  float s = 0.f;
#pragma unroll
  for (int t = 0; t < 18; t++) {
    us8 v = *(const us8*)&p[t * 512 + lane * 8];
#pragma unroll
    for (int e = 0; e < 8; e++) s += b2f(v[e]);
  }
#pragma unroll
  for (int o = 32; o; o >>= 1) s += __shfl_xor(s, o, 64);
  if (lane == 0) r[row] = s;
}

// u[b][i] = Wq[i,:].r[b,:] ; w[b][i] = Wk[i,:].r[b,:]
__global__ __launch_bounds__(256)
void matvec_uw(const u16* __restrict__ w_qkv, const float* __restrict__ r,
               float* __restrict__ u, float* __restrict__ w) {
  const int g = blockIdx.x * 256 + threadIdx.x;  // 0..8191
  const int b = g >> 10;
  const int s = (g >> 9) & 1;
  const int i = g & 511;
  const u16* Wrow = w_qkv + (long)(s * 512 + i) * 512;
  const float* rb = r + b * 512;
  float acc = 0.f;
  for (int c = 0; c < 512; c++) acc += b2f(Wrow[c]) * rb[c];
  (s ? w : u)[b * 512 + i] = acc;
}

// cv[b][o] = Wp[o,:].y[b,:] + bp[o]
__global__ __launch_bounds__(256)
void cvec(const u16* __restrict__ w_proj, const float* __restrict__ y,
          const u16* __restrict__ b_proj, float* __restrict__ cv) {
  const int g = blockIdx.x * 256 + threadIdx.x;  // 0..4095
  const int b = g >> 9;
  const int o = g & 511;
  const u16* Wrow = w_proj + (long)o * 512;
  const float* yb = y + b * 512;
  float acc = 0.f;
  for (int i = 0; i < 512; i++) acc += b2f(Wrow[i]) * yb[i];
  cv[b * 512 + o] = acc + b2f(b_proj[o]);
}

// Row softmax with rank-1 bias terms. One wave per row i.
// logits[j] = scale*(Score[i][j] + (u[i]+N*bq[i])*bk[j] + bq[i]*w[j])
// Writes PT[b][j][i] (bf16) and y[b][i] = sum_j P[i][j]*bv[j].
__global__ __launch_bounds__(256)
void softmax_rank1(const float* __restrict__ Score, const float* __restrict__ u,
                   const float* __restrict__ w, const u16* __restrict__ b_qkv,
                   u16* __restrict__ PT, float* __restrict__ y) {
  const int row  = blockIdx.x * 4 + (threadIdx.x >> 6);
  const int lane = threadIdx.x & 63;
  const int b = row >> 9, i = row & 511;
  const float scale = 0.04419417382415922f;  // 1/sqrt(512)
  const float* srow = Score + (long)row * 512;
  const float* wb = w + b * 512;
  const float bq_i = b2f(b_qkv[i]);
  const float uu = u[row] + 9216.0f * bq_i;
  float vals[8];
  float mx = -1e30f;
#pragma unroll
  for (int t = 0; t < 8; t++) {
    int j = lane + t * 64;
    float s = srow[j] + uu * b2f(b_qkv[512 + j]) + bq_i * wb[j];
    vals[t] = scale * s;
    mx = fmaxf(mx, vals[t]);
  }
#pragma unroll
  for (int o = 32; o; o >>= 1) mx = fmaxf(mx, __shfl_xor(mx, o, 64));
  float sum = 0.f, ys = 0.f;
#pragma unroll
  for (int t = 0; t < 8; t++) {
    int j = lane + t * 64;
    vals[t] = __expf(vals[t] - mx);
    sum += vals[t];
    ys += vals[t] * b2f(b_qkv[1024 + j]);
  }
#pragma unroll
  for (int o = 32; o; o >>= 1) sum += __shfl_xor(sum, o, 64);
#pragma unroll
  for (int o = 32; o; o >>= 1) ys += __shfl_xor(ys, o, 64);
  const float inv = 1.0f / sum;
#pragma unroll
  for (int t = 0; t < 8; t++) {
    int j = lane + t * 64;
    PT[(long)b * 512 * 512 + (long)j * 512 + i] = f2b(vals[t] * inv);
  }
  if (lane == 0) y[row] = ys * inv;
}

// 512x512 bf16 transpose
__global__ __launch_bounds__(256)
void transpose512(const u16* __restrict__ in, u16* __restrict__ out) {
  __shared__ u16 tile[32][33];
  const int c0 = blockIdx.x * 32, r0 = blockIdx.y * 32;
  const int tx = threadIdx.x, ty = threadIdx.y;
#pragma unroll
  for (int i = 0; i < 32; i += 8)
    tile[ty + i][tx] = in[(long)(r0 + ty + i) * 512 + c0 + tx];
  __syncthreads();
#pragma unroll
  for (int i = 0; i < 32; i += 8)
    out[(long)(c0 + ty + i) * 512 + r0 + tx] = tile[tx][ty + i];
}

extern "C" void kernel_launch(void* const* d_in, const int* in_sizes, int n_in,
                              void* d_out, int out_size, void* d_ws, size_t ws_size,
                              hipStream_t stream) {
  const long CN = 512L * 9216;
  const long SQ = 512L * 512;

  char* ws = (char*)d_ws;
  int*   flag  = (int*)ws;                      ws += 16;
  u16*   Gb    = (u16*)ws;                      ws += 8 * SQ * 2;
  u16*   T1    = (u16*)ws;                      ws += 8 * SQ * 2;
  u16*   PT    = (u16*)ws;                      ws += 8 * SQ * 2;
  u16*   T3    = (u16*)ws;                      ws += 8 * SQ * 2;
  u16*   Mm    = (u16*)ws;                      ws += 8 * SQ * 2;
  float* Score = (float*)ws;                    ws += 8 * SQ * 4;
  u16*   WvT   = (u16*)ws;                      ws += SQ * 2;
  float* r     = (float*)ws;                    ws += 8 * 512 * 4;
  float* u     = (float*)ws;                    ws += 8 * 512 * 4;
  float* w     = (float*)ws;                    ws += 8 * 512 * 4;
  float* y     = (float*)ws;                    ws += 8 * 512 * 4;
  float* cv    = (float*)ws;                    ws += 8 * 512 * 4;
  // canonical bf16 copies of inputs
  u16* xc      = (u16*)ws;                      ws += 8 * CN * 2;     // 75.5 MB
  u16* wqkv_c  = (u16*)ws;                      ws += 1536L * 512 * 2;
  u16* bqkv_c  = (u16*)ws;                      ws += 1536L * 2;
  u16* wproj_c = (u16*)ws;                      ws += 512L * 512 * 2;
  u16* bproj_c = (u16*)ws;                      ws += 512L * 2;

  char* mark1 = ws;
  // split-K fp32 partials: 8 splits x 8 batches x 10 tiles x 128x128 fp32
  float* Psk  = (float*)ws;                     ws += 8L * 8 * 10 * 16384 * 4;

  const bool full  = ((size_t)(mark1 - (char*)d_ws) <= ws_size);
  const bool full2 = ((size_t)(ws    - (char*)d_ws) <= ws_size);

  if (full) {
    detect_dtype<<<1, 256, 0, stream>>>((const u16*)d_in[0], flag, -1);
    convert_bf16<<<18432, 256, 0, stream>>>(d_in[0], xc,      8 * CN,      flag);
    convert_bf16<<<384,   256, 0, stream>>>(d_in[1], wqkv_c,  1536L * 512, flag);
    convert_bf16<<<1,     256, 0, stream>>>(d_in[2], bqkv_c,  1536,        flag);
    convert_bf16<<<128,   256, 0, stream>>>(d_in[3], wproj_c, 512L * 512,  flag);
    convert_bf16<<<1,     256, 0, stream>>>(d_in[4], bproj_c, 512,         flag);
  } else {
    // not enough scratch for copies: assume bf16 inputs, use them directly
    detect_dtype<<<1, 256, 0, stream>>>((const u16*)d_in[0], flag, 0);
    xc      = (u16*)d_in[0];
    wqkv_c  = (u16*)d_in[1];
    bqkv_c  = (u16*)d_in[2];
    wproj_c = (u16*)d_in[3];
    bproj_c = (u16*)d_in[4];
  }

  const u16* Wq = wqkv_c;
  const u16* Wk = wqkv_c + 512 * 512;
  const u16* Wv = wqkv_c + 1024 * 512;

  // 1) G[b] = X X^T (bf16, symmetric)
  if (full2) {
    gemm_xxt_splitk<<<dim3(10, 1, 64), 256, 0, stream>>>(xc, Psk);
    reduce_xxt<<<dim3(10, 8), 256, 0, stream>>>(Psk, Gb);
  } else {
    gemm_nt<u16><<<dim3(4, 4, 8), 256, 0, stream>>>(
        xc, CN, 9216, xc, CN, 9216, Gb, SQ, 512, 9216);
  }
  // 2) row sums + u,w vectors
  rowsum<<<1024, 256, 0, stream>>>(xc, r);
  matvec_uw<<<32, 256, 0, stream>>>(wqkv_c, r, u, w);
  // 3) T1 = Wq G (G symmetric -> NT with B=G)
  gemm_nt<u16><<<dim3(4, 4, 8), 256, 0, stream>>>(
      Wq, 0, 512, Gb, SQ, 512, T1, SQ, 512, 512);
  // 4) Score = T1 Wk^T
  gemm_nt<float><<<dim3(4, 4, 8), 256, 0, stream>>>(
      T1, SQ, 512, Wk, 0, 512, Score, SQ, 512, 512);
  // 5) softmax rows with rank-1 terms -> PT, y
  softmax_rank1<<<1024, 256, 0, stream>>>(Score, u, w, bqkv_c, PT, y);
  // 6) WvT
  transpose512<<<dim3(16, 16), dim3(32, 8), 0, stream>>>(Wv, WvT);
  // 7) T3 = Wp P  (NT with B=PT)
  gemm_nt<u16><<<dim3(4, 4, 8), 256, 0, stream>>>(
      wproj_c, 0, 512, PT, SQ, 512, T3, SQ, 512, 512);
  // 8) M = T3 Wv  (NT with B=WvT)
  gemm_nt<u16><<<dim3(4, 4, 8), 256, 0, stream>>>(
      T3, SQ, 512, WvT, 0, 512, Mm, SQ, 512, 512);
  // 9) cv = Wp y + bp
  cvec<<<16, 256, 0, stream>>>(wproj_c, y, bproj_c, cv);
  // 10) out = M X + cv  (output dtype per flag)
  gemm_nn_out<<<dim3(72, 4, 8), 256, 0, stream>>>(Mm, xc, cv, d_out, flag);
}

// Round 2
// 572.606 us; speedup vs baseline: 1.3234x; 1.0314x over previous
//
#include <hip/hip_runtime.h>

typedef unsigned short u16;
typedef unsigned long long u64;
typedef __bf16 bf16x8 __attribute__((ext_vector_type(8)));
typedef u16 us8 __attribute__((ext_vector_type(8)));
typedef u16 us4 __attribute__((ext_vector_type(4)));
typedef float floatx4 __attribute__((ext_vector_type(4)));
typedef float f32x4 __attribute__((ext_vector_type(4)));

__device__ inline float b2f(u16 u) {
  union { unsigned u; float f; } x; x.u = ((unsigned)u) << 16; return x.f;
}
__device__ inline u16 f2b(float f) {
  union { float f; unsigned u; } x; x.f = f;
  unsigned r = x.u + 0x7fffu + ((x.u >> 16) & 1u);
  return (u16)(r >> 16);
}

// Probe first 4096 u16 words of x. bf16 data: max|v| ~ 5.7. fp32 data read
// as bf16: low mantissa halves are ~uniform u16 -> |v|>1000 w.p. ~0.46 each.
// force >= 0 overrides (small-ws fallback).
__global__ __launch_bounds__(256)
void detect_dtype(const u16* __restrict__ x, int* __restrict__ flag, int force) {
  __shared__ float sm[4];
  const int t = threadIdx.x;
  float m = 0.f;
  for (int i = t; i < 4096; i += 256) {
    float v = fabsf(b2f(x[i]));
    if (v > m) m = v;  // NaN compares false -> skipped; inf caught
  }
#pragma unroll
  for (int o = 32; o; o >>= 1) m = fmaxf(m, __shfl_xor(m, o, 64));
  if ((t & 63) == 0) sm[t >> 6] = m;
  __syncthreads();
  if (t == 0) {
    float mm = fmaxf(fmaxf(sm[0], sm[1]), fmaxf(sm[2], sm[3]));
    *flag = (force >= 0) ? force : (mm > 1000.0f ? 1 : 0);
  }
}

// Canonicalize an input to bf16: copy (bf16 in) or downconvert (fp32 in).
__global__ __launch_bounds__(256)
void convert_bf16(const void* __restrict__ in, u16* __restrict__ out, long n,
                  const int* __restrict__ flag) {
  const long i = (blockIdx.x * 256L + threadIdx.x) * 8;
  if (i >= n) return;
  if (*flag) {
    const float* p = (const float*)in + i;
    f32x4 a = ((const f32x4*)p)[0];
    f32x4 b = ((const f32x4*)p)[1];
    us8 o;
#pragma unroll
    for (int j = 0; j < 4; j++) { o[j] = f2b(a[j]); o[j + 4] = f2b(b[j]); }
    *(us8*)(out + i) = o;
  } else {
    *(us8*)(out + i) = *((const us8*)in + (i >> 3));
  }
}

// D[M][N] = A[M][K] . B[N][K]^T ; A,B K-contiguous (NT). 128x128 tile,
// 4 waves of 64x64, mfma_f32_16x16x32_bf16, fp32 accum.
// LDS XOR swizzle: 16B slot s at row r stored at slot s^((r>>1)&3).
template <typename OutT>
__global__ __launch_bounds__(256)
void gemm_nt(const u16* __restrict__ A, long sA, int lda,
             const u16* __restrict__ B, long sB, int ldb,
             OutT* __restrict__ D, long sD, int ldd, int K) {
  __shared__ __align__(16) u16 As[128 * 32];
  __shared__ __align__(16) u16 Bs[128 * 32];
  const int bz = blockIdx.z;
  const u16* Ab = A + (long)bz * sA;
  const u16* Bb = B + (long)bz * sB;
  OutT* Db = D + (long)bz * sD;
  const int tid  = threadIdx.x;
  const int lane = tid & 63;
  const int wave = tid >> 6;
  const int wm = (wave >> 1) * 64, wn = (wave & 1) * 64;
  const int m0 = blockIdx.y * 128, n0 = blockIdx.x * 128;
  const int srow = tid >> 2;
  const int ss   = tid & 3;                       // 16B slot (global side)
  const int sw   = (ss ^ ((srow >> 1) & 3)) * 8;  // swizzled LDS slot (elems)
  const int lr = lane & 15;
  const int rsw = (((lane >> 4) ^ ((lr >> 1) & 3)) * 8);  // swizzled read slot

  floatx4 acc[4][4];
#pragma unroll
  for (int i = 0; i < 4; i++)
#pragma unroll
    for (int j = 0; j < 4; j++) acc[i][j] = (floatx4){0.f, 0.f, 0.f, 0.f};

  for (int k0 = 0; k0 < K; k0 += 32) {
    __syncthreads();
    *(bf16x8*)&As[srow * 32 + sw] =
        *(const bf16x8*)&Ab[(long)(m0 + srow) * lda + k0 + ss * 8];
    *(bf16x8*)&As[(srow + 64) * 32 + sw] =
        *(const bf16x8*)&Ab[(long)(m0 + srow + 64) * lda + k0 + ss * 8];
    *(bf16x8*)&Bs[srow * 32 + sw] =
        *(const bf16x8*)&Bb[(long)(n0 + srow) * ldb + k0 + ss * 8];
    *(bf16x8*)&Bs[(srow + 64) * 32 + sw] =
        *(const bf16x8*)&Bb[(long)(n0 + srow + 64) * ldb + k0 + ss * 8];
    __syncthreads();
    bf16x8 af[4], bfr[4];
#pragma unroll
    for (int i = 0; i < 4; i++)
      af[i] = *(bf16x8*)&As[(wm + i * 16 + lr) * 32 + rsw];
#pragma unroll
    for (int i = 0; i < 4; i++)
      bfr[i] = *(bf16x8*)&Bs[(wn + i * 16 + lr) * 32 + rsw];
#pragma unroll
    for (int mi = 0; mi < 4; mi++)
#pragma unroll
      for (int ni = 0; ni < 4; ni++)
        acc[mi][ni] = __builtin_amdgcn_mfma_f32_16x16x32_bf16(
            af[mi], bfr[ni], acc[mi][ni], 0, 0, 0);
  }

  // C/D layout (m89-verified): col = lane&15, row = (lane>>4)*4 + reg
  const int lc  = lane & 15;
  const int lr4 = (lane >> 4) * 4;
#pragma unroll
  for (int mi = 0; mi < 4; mi++) {
#pragma unroll
    for (int r = 0; r < 4; r++) {
      int gm = m0 + wm + mi * 16 + lr4 + r;
#pragma unroll
      for (int ni = 0; ni < 4; ni++) {
        int gn = n0 + wn + ni * 16 + lc;
        float v = acc[mi][ni][r];
        if constexpr (sizeof(OutT) == 4) Db[(long)gm * ldd + gn] = v;
        else                             Db[(long)gm * ldd + gn] = f2b(v);
      }
    }
  }
}

// ---- split-K symmetric XX^T --------------------------------------------
__device__ inline void tile_decode(int t, int& by, int& bx) {
  by = (int)((sqrtf((float)(8 * t + 1)) - 1.0f) * 0.5f);
  bx = t - (by * (by + 1)) / 2;
}

__global__ __launch_bounds__(256)
void gemm_xxt_splitk(const u16* __restrict__ X, float* __restrict__ P) {
  __shared__ __align__(16) u16 As[128 * 32];
  __shared__ __align__(16) u16 Bs[128 * 32];
  const int t  = blockIdx.x;        // 0..9
  const int bz = blockIdx.z >> 3;   // batch
  const int sp = blockIdx.z & 7;    // k-split
  int by, bx;
  tile_decode(t, by, bx);
  const int m0 = by * 128, n0 = bx * 128;
  const u16* Xb = X + (long)bz * 512 * 9216;
  const int tid  = threadIdx.x;
  const int lane = tid & 63;
  const int wave = tid >> 6;
  const int wm = (wave >> 1) * 64, wn = (wave & 1) * 64;
  const int srow = tid >> 2;
  const int ss   = tid & 3;
  const int sw   = (ss ^ ((srow >> 1) & 3)) * 8;
  const int lr = lane & 15;
  const int rsw = (((lane >> 4) ^ ((lr >> 1) & 3)) * 8);

  floatx4 acc[4][4];
#pragma unroll
  for (int i = 0; i < 4; i++)
#pragma unroll
    for (int j = 0; j < 4; j++) acc[i][j] = (floatx4){0.f, 0.f, 0.f, 0.f};

  const int k0beg = sp * 1152;
  for (int k0 = k0beg; k0 < k0beg + 1152; k0 += 32) {
    __syncthreads();
    *(bf16x8*)&As[srow * 32 + sw] =
        *(const bf16x8*)&Xb[(long)(m0 + srow) * 9216 + k0 + ss * 8];
    *(bf16x8*)&As[(srow + 64) * 32 + sw] =
        *(const bf16x8*)&Xb[(long)(m0 + srow + 64) * 9216 + k0 + ss * 8];
    *(bf16x8*)&Bs[srow * 32 + sw] =
        *(const bf16x8*)&Xb[(long)(n0 + srow) * 9216 + k0 + ss * 8];
    *(bf16x8*)&Bs[(srow + 64) * 32 + sw] =
        *(const bf16x8*)&Xb[(long)(n0 + srow + 64) * 9216 + k0 + ss * 8];
    __syncthreads();
    bf16x8 af[4], bfr[4];
#pragma unroll
    for (int i = 0; i < 4; i++)
      af[i] = *(bf16x8*)&As[(wm + i * 16 + lr) * 32 + rsw];
#pragma unroll
    for (int i = 0; i < 4; i++)
      bfr[i] = *(bf16x8*)&Bs[(wn + i * 16 + lr) * 32 + rsw];
#pragma unroll
    for (int mi = 0; mi < 4; mi++)
#pragma unroll
      for (int ni = 0; ni < 4; ni++)
        acc[mi][ni] = __builtin_amdgcn_mfma_f32_16x16x32_bf16(
            af[mi], bfr[ni], acc[mi][ni], 0, 0, 0);
  }

  float* Pb = P + ((long)(sp * 8 + bz) * 10 + t) * 16384;
  const int lc  = lane & 15;
  const int lr4 = (lane >> 4) * 4;
#pragma unroll
  for (int mi = 0; mi < 4; mi++)
#pragma unroll
    for (int r = 0; r < 4; r++) {
      int gm = wm + mi * 16 + lr4 + r;
#pragma unroll
      for (int ni = 0; ni < 4; ni++)
        Pb[gm * 128 + wn + ni * 16 + lc] = acc[mi][ni][r];
    }
}

// Sum the 8 split partials of tile t (batch bz), convert to bf16, write the
// tile and (for off-diagonal tiles) its mirror via an LDS transpose.
__global__ __launch_bounds__(256)
void reduce_xxt(const float* __restrict__ P, u16* __restrict__ G) {
  __shared__ u16 tl[128][130];
  const int t = blockIdx.x, bz = blockIdx.y;
  int by, bx;
  tile_decode(t, by, bx);
  const int m0 = by * 128, n0 = bx * 128;
  u16* Gb = G + (long)bz * 512 * 512;
  for (int e = threadIdx.x; e < 4096; e += 256) {
    const int idx = e * 4;
    const int m = idx >> 7, n = idx & 127;
    f32x4 s = {0.f, 0.f, 0.f, 0.f};
#pragma unroll
    for (int sp = 0; sp < 8; sp++) {
      f32x4 v = *(const f32x4*)&P[(((long)sp * 8 + bz) * 10 + t) * 16384 + idx];
      s.x += v.x; s.y += v.y; s.z += v.z; s.w += v.w;
    }
    us4 o = {f2b(s.x), f2b(s.y), f2b(s.z), f2b(s.w)};
    *(us4*)&Gb[(long)(m0 + m) * 512 + n0 + n] = o;
    tl[m][n] = o[0]; tl[m][n + 1] = o[1]; tl[m][n + 2] = o[2]; tl[m][n + 3] = o[3];
  }
  if (m0 == n0) return;
  __syncthreads();
  for (int e = threadIdx.x; e < 4096; e += 256) {
    const int idx = e * 4;
    const int nr = idx >> 7, mc = idx & 127;
    us4 o = {tl[mc][nr], tl[mc + 1][nr], tl[mc + 2][nr], tl[mc + 3][nr]};
    *(us4*)&Gb[(long)(n0 + nr) * 512 + m0 + mc] = o;
  }
}

// out[b][o][n] = sum_c M[b][o][c] * X[b][c][n] + bias[b][o]  (NN GEMM)
// B-side: X tile staged in LDS as [nb][s][4][16] 128B subtiles (natural
// k-major b128 writes, <=2-way banks), fragments built with
// ds_read_b64_tr_b16: per-lane addr subtile_base + (lane&15)*8 delivers
// column lane&15, rows j=k&3 -> MFMA B-frag layout. offset:0/128 gives
// k = 8g..8g+3 / 8g+4..8g+7 for lane group g.
__global__ __launch_bounds__(256)
void gemm_nn_out(const u16* __restrict__ A, const u16* __restrict__ B,
                 const float* __restrict__ bias, void* __restrict__ Dout,
                 const int* __restrict__ flag) {
  __shared__ __align__(16)  u16 As[128 * 32];
  __shared__ __align__(128) u16 Bs[32 * 128];  // subtiled, 8KB
  const int f = *flag;
  const int bz = blockIdx.z;
  const u16* Ab = A + (long)bz * 512 * 512;
  const u16* Bb = B + (long)bz * 512 * 9216;
  const float* cb = bias + bz * 512;
  const int tid  = threadIdx.x;
  const int lane = tid & 63;
  const int wave = tid >> 6;
  const int wm = (wave >> 1) * 64, wn = (wave & 1) * 64;
  const int m0 = blockIdx.y * 128, n0 = blockIdx.x * 128;
  const int srow = tid >> 2;
  const int ss   = tid & 3;
  const int sw   = (ss ^ ((srow >> 1) & 3)) * 8;
  const int kk  = tid >> 3;         // 0..31 (k within tile)
  const int nbw = tid & 7;          // n-block 0..7 (16 n each)
  const int lr = lane & 15;
  const int rsw = (((lane >> 4) ^ ((lr >> 1) & 3)) * 8);
  // staging dest (u16 units): subtile (nbw, kk>>2), row kk&3, half 0
  const int stO = (nbw * 8 + (kk >> 2)) * 64 + (kk & 3) * 16;
  // tr_read per-lane byte address (fragment ni adds ni*1024):
  const unsigned bsBase = (unsigned)(size_t)(&Bs[0]);
  const unsigned trA = bsBase + (unsigned)((wn >> 4) * 1024 +
                       (lane >> 4) * 256 + (lane & 15) * 8);

  floatx4 acc[4][4];
#pragma unroll
  for (int i = 0; i < 4; i++)
#pragma unroll
    for (int j = 0; j < 4; j++) acc[i][j] = (floatx4){0.f, 0.f, 0.f, 0.f};

  for (int k0 = 0; k0 < 512; k0 += 32) {
    __syncthreads();
    *(bf16x8*)&As[srow * 32 + sw] =
        *(const bf16x8*)&Ab[(long)(m0 + srow) * 512 + k0 + ss * 8];
    *(bf16x8*)&As[(srow + 64) * 32 + sw] =
        *(const bf16x8*)&Ab[(long)(m0 + srow + 64) * 512 + k0 + ss * 8];
    us8 v0 = *(const us8*)&Bb[(long)(k0 + kk) * 9216 + n0 + nbw * 16];
    us8 v1 = *(const us8*)&Bb[(long)(k0 + kk) * 9216 + n0 + nbw * 16 + 8];
    *(us8*)&Bs[stO]     = v0;
    *(us8*)&Bs[stO + 8] = v1;
    __syncthreads();
    bf16x8 af[4];
#pragma unroll
    for (int i = 0; i < 4; i++)
      af[i] = *(bf16x8*)&As[(wm + i * 16 + lr) * 32 + rsw];
    u64 blo[4], bhi[4];
#pragma unroll
    for (int ni = 0; ni < 4; ni++) {
      unsigned a = trA + ni * 1024;
      asm volatile("ds_read_b64_tr_b16 %0, %1" : "=v"(blo[ni]) : "v"(a));
      asm volatile("ds_read_b64_tr_b16 %0, %1 offset:128" : "=v"(bhi[ni]) : "v"(a));
    }
    asm volatile("s_waitcnt lgkmcnt(0)" ::: "memory");
    __builtin_amdgcn_sched_barrier(0);
    bf16x8 bfr[4];
#pragma unroll
    for (int ni = 0; ni < 4; ni++) {
      union { u64 q[2]; bf16x8 v; } u;
      u.q[0] = blo[ni]; u.q[1] = bhi[ni];
      bfr[ni] = u.v;
    }
#pragma unroll
    for (int mi = 0; mi < 4; mi++)
#pragma unroll
      for (int ni = 0; ni < 4; ni++)
        acc[mi][ni] = __builtin_amdgcn_mfma_f32_16x16x32_bf16(
            af[mi], bfr[ni], acc[mi][ni], 0, 0, 0);
  }

  const int lc  = lane & 15;
  const int lr4 = (lane >> 4) * 4;
  if (f) {
    float* Db = (float*)Dout + (long)bz * 512 * 9216;
#pragma unroll
    for (int mi = 0; mi < 4; mi++)
#pragma unroll
      for (int r = 0; r < 4; r++) {
        int gm = m0 + wm + mi * 16 + lr4 + r;
        float bv = cb[gm];
#pragma unroll
        for (int ni = 0; ni < 4; ni++)
          Db[(long)gm * 9216 + n0 + wn + ni * 16 + lc] = acc[mi][ni][r] + bv;
      }
  } else {
    u16* Db = (u16*)Dout + (long)bz * 512 * 9216;
#pragma unroll
    for (int mi = 0; mi < 4; mi++)
#pragma unroll
      for (int r = 0; r < 4; r++) {
        int gm = m0 + wm + mi * 16 + lr4 + r;
        float bv = cb[gm];
#pragma unroll
        for (int ni = 0; ni < 4; ni++)
          Db[(long)gm * 9216 + n0 + wn + ni * 16 + lc] = f2b(acc[mi][ni][r] + bv);
      }
  }
}

// r[b][c] = sum_n x[b][c][n]. One wave per row.
__global__ __launch_bounds__(256)
void rowsum(const u16* __restrict__ x, float* __restrict__ r) {
  const int row  = blockIdx.x * 4 + (threadIdx.x >> 6);
  const int lane = threadIdx.x & 63;
  const u16* p = x + (long)row * 9216;
  float s = 0.f;
#pragma unroll
  for (int t = 0; t < 18; t++) {
    us8 v = *(const us8*)&p[t * 512 + lane * 8];
#pragma unroll
    for (int e = 0; e < 8; e++) s += b2f(v[e]);
  }
#pragma unroll
  for (int o = 32; o; o >>= 1) s += __shfl_xor(s, o, 64);
  if (lane == 0) r[row] = s;
}

// u[b][i] = Wq[i,:].r[b,:] ; w[b][i] = Wk[i,:].r[b,:]
__global__ __launch_bounds__(256)
void matvec_uw(const u16* __restrict__ w_qkv, const float* __restrict__ r,
               float* __restrict__ u, float* __restrict__ w) {
  const int g = blockIdx.x * 256 + threadIdx.x;  // 0..8191
  const int b = g >> 10;
  const int s = (g >> 9) & 1;
  const int i = g & 511;
  const u16* Wrow = w_qkv + (long)(s * 512 + i) * 512;
  const float* rb = r + b * 512;
  float acc = 0.f;
  for (int c = 0; c < 512; c++) acc += b2f(Wrow[c]) * rb[c];
  (s ? w : u)[b * 512 + i] = acc;
}

// cv[b][o] = Wp[o,:].y[b,:] + bp[o]
__global__ __launch_bounds__(256)
void cvec(const u16* __restrict__ w_proj, const float* __restrict__ y,
          const u16* __restrict__ b_proj, float* __restrict__ cv) {
  const int g = blockIdx.x * 256 + threadIdx.x;  // 0..4095
  const int b = g >> 9;
  const int o = g & 511;
  const u16* Wrow = w_proj + (long)o * 512;
  const float* yb = y + b * 512;
  float acc = 0.f;
  for (int i = 0; i < 512; i++) acc += b2f(Wrow[i]) * yb[i];
  cv[b * 512 + o] = acc + b2f(b_proj[o]);
}

// Row softmax with rank-1 bias terms. One wave per row i.
__global__ __launch_bounds__(256)
void softmax_rank1(const float* __restrict__ Score, const float* __restrict__ u,
                   const float* __restrict__ w, const u16* __restrict__ b_qkv,
                   u16* __restrict__ PT, float* __restrict__ y) {
  const int row  = blockIdx.x * 4 + (threadIdx.x >> 6);
  const int lane = threadIdx.x & 63;
  const int b = row >> 9, i = row & 511;
  const float scale = 0.04419417382415922f;  // 1/sqrt(512)
  const float* srow = Score + (long)row * 512;
  const float* wb = w + b * 512;
  const float bq_i = b2f(b_qkv[i]);
  const float uu = u[row] + 9216.0f * bq_i;
  float vals[8];
  float mx = -1e30f;
#pragma unroll
  for (int t = 0; t < 8; t++) {
    int j = lane + t * 64;
    float s = srow[j] + uu * b2f(b_qkv[512 + j]) + bq_i * wb[j];
    vals[t] = scale * s;
    mx = fmaxf(mx, vals[t]);
  }
#pragma unroll
  for (int o = 32; o; o >>= 1) mx = fmaxf(mx, __shfl_xor(mx, o, 64));
  float sum = 0.f, ys = 0.f;
#pragma unroll
  for (int t = 0; t < 8; t++) {
    int j = lane + t * 64;
    vals[t] = __expf(vals[t] - mx);
    sum += vals[t];
    ys += vals[t] * b2f(b_qkv[1024 + j]);
  }
#pragma unroll
  for (int o = 32; o; o >>= 1) sum += __shfl_xor(sum, o, 64);
#pragma unroll
  for (int o = 32; o; o >>= 1) ys += __shfl_xor(ys, o, 64);
  const float inv = 1.0f / sum;
#pragma unroll
  for (int t = 0; t < 8; t++) {
    int j = lane + t * 64;
    PT[(long)b * 512 * 512 + (long)j * 512 + i] = f2b(vals[t] * inv);
  }
  if (lane == 0) y[row] = ys * inv;
}

// 512x512 bf16 transpose
__global__ __launch_bounds__(256)
void transpose512(const u16* __restrict__ in, u16* __restrict__ out) {
  __shared__ u16 tile[32][33];
  const int c0 = blockIdx.x * 32, r0 = blockIdx.y * 32;
  const int tx = threadIdx.x, ty = threadIdx.y;
#pragma unroll
  for (int i = 0; i < 32; i += 8)
    tile[ty + i][tx] = in[(long)(r0 + ty + i) * 512 + c0 + tx];
  __syncthreads();
#pragma unroll
  for (int i = 0; i < 32; i += 8)
    out[(long)(c0 + ty + i) * 512 + r0 + tx] = tile[tx][ty + i];
}

extern "C" void kernel_launch(void* const* d_in, const int* in_sizes, int n_in,
                              void* d_out, int out_size, void* d_ws, size_t ws_size,
                              hipStream_t stream) {
  const long CN = 512L * 9216;
  const long SQ = 512L * 512;

  char* ws = (char*)d_ws;
  int*   flag  = (int*)ws;                      ws += 16;
  u16*   Gb    = (u16*)ws;                      ws += 8 * SQ * 2;
  u16*   T1    = (u16*)ws;                      ws += 8 * SQ * 2;
  u16*   PT    = (u16*)ws;                      ws += 8 * SQ * 2;
  u16*   T3    = (u16*)ws;                      ws += 8 * SQ * 2;
  u16*   Mm    = (u16*)ws;                      ws += 8 * SQ * 2;
  float* Score = (float*)ws;                    ws += 8 * SQ * 4;
  u16*   WvT   = (u16*)ws;                      ws += SQ * 2;
  float* r     = (float*)ws;                    ws += 8 * 512 * 4;
  float* u     = (float*)ws;                    ws += 8 * 512 * 4;
  float* w     = (float*)ws;                    ws += 8 * 512 * 4;
  float* y     = (float*)ws;                    ws += 8 * 512 * 4;
  float* cv    = (float*)ws;                    ws += 8 * 512 * 4;
  // canonical bf16 copies of inputs
  u16* xc      = (u16*)ws;                      ws += 8 * CN * 2;     // 75.5 MB
  u16* wqkv_c  = (u16*)ws;                      ws += 1536L * 512 * 2;
  u16* bqkv_c  = (u16*)ws;                      ws += 1536L * 2;
  u16* wproj_c = (u16*)ws;                      ws += 512L * 512 * 2;
  u16* bproj_c = (u16*)ws;                      ws += 512L * 2;

  char* mark1 = ws;
  // split-K fp32 partials: 8 splits x 8 batches x 10 tiles x 128x128 fp32
  float* Psk  = (float*)ws;                     ws += 8L * 8 * 10 * 16384 * 4;

  const bool full  = ((size_t)(mark1 - (char*)d_ws) <= ws_size);
  const bool full2 = ((size_t)(ws    - (char*)d_ws) <= ws_size);

  if (full) {
    detect_dtype<<<1, 256, 0, stream>>>((const u16*)d_in[0], flag, -1);
    convert_bf16<<<18432, 256, 0, stream>>>(d_in[0], xc,      8 * CN,      flag);
    convert_bf16<<<384,   256, 0, stream>>>(d_in[1], wqkv_c,  1536L * 512, flag);
    convert_bf16<<<1,     256, 0, stream>>>(d_in[2], bqkv_c,  1536,        flag);
    convert_bf16<<<128,   256, 0, stream>>>(d_in[3], wproj_c, 512L * 512,  flag);
    convert_bf16<<<1,     256, 0, stream>>>(d_in[4], bproj_c, 512,         flag);
  } else {
    // not enough scratch for copies: assume bf16 inputs, use them directly
    detect_dtype<<<1, 256, 0, stream>>>((const u16*)d_in[0], flag, 0);
    xc      = (u16*)d_in[0];
    wqkv_c  = (u16*)d_in[1];
    bqkv_c  = (u16*)d_in[2];
    wproj_c = (u16*)d_in[3];
    bproj_c = (u16*)d_in[4];
  }

  const u16* Wq = wqkv_c;
  const u16* Wk = wqkv_c + 512 * 512;
  const u16* Wv = wqkv_c + 1024 * 512;

  // 1) G[b] = X X^T (bf16, symmetric)
  if (full2) {
    gemm_xxt_splitk<<<dim3(10, 1, 64), 256, 0, stream>>>(xc, Psk);
    reduce_xxt<<<dim3(10, 8), 256, 0, stream>>>(Psk, Gb);
  } else {
    gemm_nt<u16><<<dim3(4, 4, 8), 256, 0, stream>>>(
        xc, CN, 9216, xc, CN, 9216, Gb, SQ, 512, 9216);
  }
  // 2) row sums + u,w vectors
  rowsum<<<1024, 256, 0, stream>>>(xc, r);
  matvec_uw<<<32, 256, 0, stream>>>(wqkv_c, r, u, w);
  // 3) T1 = Wq G (G symmetric -> NT with B=G)
  gemm_nt<u16><<<dim3(4, 4, 8), 256, 0, stream>>>(
      Wq, 0, 512, Gb, SQ, 512, T1, SQ, 512, 512);
  // 4) Score = T1 Wk^T
  gemm_nt<float><<<dim3(4, 4, 8), 256, 0, stream>>>(
      T1, SQ, 512, Wk, 0, 512, Score, SQ, 512, 512);
  // 5) softmax rows with rank-1 terms -> PT, y
  softmax_rank1<<<1024, 256, 0, stream>>>(Score, u, w, bqkv_c, PT, y);
  // 6) WvT
  transpose512<<<dim3(16, 16), dim3(32, 8), 0, stream>>>(Wv, WvT);
  // 7) T3 = Wp P  (NT with B=PT)
  gemm_nt<u16><<<dim3(4, 4, 8), 256, 0, stream>>>(
      wproj_c, 0, 512, PT, SQ, 512, T3, SQ, 512, 512);
  // 8) M = T3 Wv  (NT with B=WvT)
  gemm_nt<u16><<<dim3(4, 4, 8), 256, 0, stream>>>(
      T3, SQ, 512, WvT, 0, 512, Mm, SQ, 512, 512);
  // 9) cv = Wp y + bp
  cvec<<<16, 256, 0, stream>>>(wproj_c, y, bproj_c, cv);
  // 10) out = M X + cv  (output dtype per flag)
  gemm_nn_out<<<dim3(72, 4, 8), 256, 0, stream>>>(Mm, xc, cv, d_out, flag);
}

// Round 3
// 550.405 us; speedup vs baseline: 1.3768x; 1.0403x over previous
//
#include <hip/hip_runtime.h>

typedef unsigned short u16;
typedef unsigned long long u64;
typedef __bf16 bf16x8 __attribute__((ext_vector_type(8)));
typedef u16 us8 __attribute__((ext_vector_type(8)));
typedef u16 us4 __attribute__((ext_vector_type(4)));
typedef float floatx4 __attribute__((ext_vector_type(4)));
typedef float f32x4 __attribute__((ext_vector_type(4)));

__device__ inline float b2f(u16 u) {
  union { unsigned u; float f; } x; x.u = ((unsigned)u) << 16; return x.f;
}
__device__ inline u16 f2b(float f) {
  union { float f; unsigned u; } x; x.f = f;
  unsigned r = x.u + 0x7fffu + ((x.u >> 16) & 1u);
  return (u16)(r >> 16);
}

// async global->LDS DMA, 16B per lane. LDS dest = wave-uniform base +
// lane*16 (m104); source is per-lane. Swizzles live on the SOURCE (m173).
__device__ __forceinline__ void gl_lds16(const u16* g, void* l) {
  __builtin_amdgcn_global_load_lds(
      (const __attribute__((address_space(1))) void*)g,
      (__attribute__((address_space(3))) void*)l, 16, 0, 0);
}

// Probe first 4096 u16 words of x. bf16 data: max|v| ~ 5.7. fp32 data read
// as bf16: low mantissa halves are ~uniform u16 -> |v|>1000 w.p. ~0.46 each.
__global__ __launch_bounds__(256)
void detect_dtype(const u16* __restrict__ x, int* __restrict__ flag, int force) {
  __shared__ float sm[4];
  const int t = threadIdx.x;
  float m = 0.f;
  for (int i = t; i < 4096; i += 256) {
    float v = fabsf(b2f(x[i]));
    if (v > m) m = v;  // NaN compares false -> skipped; inf caught
  }
#pragma unroll
  for (int o = 32; o; o >>= 1) m = fmaxf(m, __shfl_xor(m, o, 64));
  if ((t & 63) == 0) sm[t >> 6] = m;
  __syncthreads();
  if (t == 0) {
    float mm = fmaxf(fmaxf(sm[0], sm[1]), fmaxf(sm[2], sm[3]));
    *flag = (force >= 0) ? force : (mm > 1000.0f ? 1 : 0);
  }
}

// Canonicalize an input to bf16: copy (bf16 in) or downconvert (fp32 in).
__global__ __launch_bounds__(256)
void convert_bf16(const void* __restrict__ in, u16* __restrict__ out, long n,
                  const int* __restrict__ flag) {
  const long i = (blockIdx.x * 256L + threadIdx.x) * 8;
  if (i >= n) return;
  if (*flag) {
    const float* p = (const float*)in + i;
    f32x4 a = ((const f32x4*)p)[0];
    f32x4 b = ((const f32x4*)p)[1];
    us8 o;
#pragma unroll
    for (int j = 0; j < 4; j++) { o[j] = f2b(a[j]); o[j + 4] = f2b(b[j]); }
    *(us8*)(out + i) = o;
  } else {
    *(us8*)(out + i) = *((const us8*)in + (i >> 3));
  }
}

// D[M][N] = A[M][K] . B[N][K]^T ; A,B K-contiguous (NT). 64x64 tile,
// 4 waves of 32x32, global_load_lds staging, source-side XOR swizzle.
template <typename OutT>
__global__ __launch_bounds__(256)
void gemm_nt(const u16* __restrict__ A, long sA, int lda,
             const u16* __restrict__ B, long sB, int ldb,
             OutT* __restrict__ D, long sD, int ldd, int K) {
  __shared__ __align__(16) u16 As[64 * 32];
  __shared__ __align__(16) u16 Bs[64 * 32];
  const int bz = blockIdx.z;
  const u16* Ab = A + (long)bz * sA;
  const u16* Bb = B + (long)bz * sB;
  OutT* Db = D + (long)bz * sD;
  const int tid  = threadIdx.x;
  const int lane = tid & 63;
  const int wave = tid >> 6;
  const int wm = (wave >> 1) * 32, wn = (wave & 1) * 32;
  const int m0 = blockIdx.y * 64, n0 = blockIdx.x * 64;
  const int srow = tid >> 2;
  const int ss   = tid & 3;
  const int sco  = (ss ^ ((srow >> 1) & 3)) * 8;  // swizzled SOURCE slot
  const int lr = lane & 15;
  const int rsw = (((lane >> 4) ^ ((lr >> 1) & 3)) * 8);  // swizzled read slot
  char* asb = (char*)As + wave * 1024;
  char* bsb = (char*)Bs + wave * 1024;

  floatx4 acc[2][2];
#pragma unroll
  for (int i = 0; i < 2; i++)
#pragma unroll
    for (int j = 0; j < 2; j++) acc[i][j] = (floatx4){0.f, 0.f, 0.f, 0.f};

  for (int k0 = 0; k0 < K; k0 += 32) {
    __syncthreads();
    gl_lds16(&Ab[(long)(m0 + srow) * lda + k0 + sco], asb);
    gl_lds16(&Bb[(long)(n0 + srow) * ldb + k0 + sco], bsb);
    __syncthreads();
    bf16x8 af[2], bfr[2];
#pragma unroll
    for (int i = 0; i < 2; i++)
      af[i] = *(bf16x8*)&As[(wm + i * 16 + lr) * 32 + rsw];
#pragma unroll
    for (int i = 0; i < 2; i++)
      bfr[i] = *(bf16x8*)&Bs[(wn + i * 16 + lr) * 32 + rsw];
#pragma unroll
    for (int mi = 0; mi < 2; mi++)
#pragma unroll
      for (int ni = 0; ni < 2; ni++)
        acc[mi][ni] = __builtin_amdgcn_mfma_f32_16x16x32_bf16(
            af[mi], bfr[ni], acc[mi][ni], 0, 0, 0);
  }

  // C/D layout (m89-verified): col = lane&15, row = (lane>>4)*4 + reg
  const int lc  = lane & 15;
  const int lr4 = (lane >> 4) * 4;
#pragma unroll
  for (int mi = 0; mi < 2; mi++) {
#pragma unroll
    for (int r = 0; r < 4; r++) {
      int gm = m0 + wm + mi * 16 + lr4 + r;
#pragma unroll
      for (int ni = 0; ni < 2; ni++) {
        int gn = n0 + wn + ni * 16 + lc;
        float v = acc[mi][ni][r];
        if constexpr (sizeof(OutT) == 4) Db[(long)gm * ldd + gn] = v;
        else                             Db[(long)gm * ldd + gn] = f2b(v);
      }
    }
  }
}

// ---- split-K symmetric XX^T --------------------------------------------
__device__ inline void tile_decode(int t, int& by, int& bx) {
  by = (int)((sqrtf((float)(8 * t + 1)) - 1.0f) * 0.5f);
  bx = t - (by * (by + 1)) / 2;
}

__global__ __launch_bounds__(256)
void gemm_xxt_splitk(const u16* __restrict__ X, float* __restrict__ P) {
  __shared__ __align__(16) u16 As[128 * 32];
  __shared__ __align__(16) u16 Bs[128 * 32];
  const int t  = blockIdx.x;        // 0..9
  const int bz = blockIdx.z >> 3;   // batch
  const int sp = blockIdx.z & 7;    // k-split
  int by, bx;
  tile_decode(t, by, bx);
  const int m0 = by * 128, n0 = bx * 128;
  const u16* Xb = X + (long)bz * 512 * 9216;
  const int tid  = threadIdx.x;
  const int lane = tid & 63;
  const int wave = tid >> 6;
  const int wm = (wave >> 1) * 64, wn = (wave & 1) * 64;
  const int srow = tid >> 2;
  const int ss   = tid & 3;
  const int sco  = (ss ^ ((srow >> 1) & 3)) * 8;
  const int lr = lane & 15;
  const int rsw = (((lane >> 4) ^ ((lr >> 1) & 3)) * 8);
  char* asb = (char*)As + wave * 1024;
  char* bsb = (char*)Bs + wave * 1024;

  floatx4 acc[4][4];
#pragma unroll
  for (int i = 0; i < 4; i++)
#pragma unroll
    for (int j = 0; j < 4; j++) acc[i][j] = (floatx4){0.f, 0.f, 0.f, 0.f};

  const int k0beg = sp * 1152;
  for (int k0 = k0beg; k0 < k0beg + 1152; k0 += 32) {
    __syncthreads();
    gl_lds16(&Xb[(long)(m0 + srow) * 9216 + k0 + sco], asb);
    gl_lds16(&Xb[(long)(m0 + 64 + srow) * 9216 + k0 + sco], asb + 4096);
    gl_lds16(&Xb[(long)(n0 + srow) * 9216 + k0 + sco], bsb);
    gl_lds16(&Xb[(long)(n0 + 64 + srow) * 9216 + k0 + sco], bsb + 4096);
    __syncthreads();
    bf16x8 af[4], bfr[4];
#pragma unroll
    for (int i = 0; i < 4; i++)
      af[i] = *(bf16x8*)&As[(wm + i * 16 + lr) * 32 + rsw];
#pragma unroll
    for (int i = 0; i < 4; i++)
      bfr[i] = *(bf16x8*)&Bs[(wn + i * 16 + lr) * 32 + rsw];
#pragma unroll
    for (int mi = 0; mi < 4; mi++)
#pragma unroll
      for (int ni = 0; ni < 4; ni++)
        acc[mi][ni] = __builtin_amdgcn_mfma_f32_16x16x32_bf16(
            af[mi], bfr[ni], acc[mi][ni], 0, 0, 0);
  }

  float* Pb = P + ((long)(sp * 8 + bz) * 10 + t) * 16384;
  const int lc  = lane & 15;
  const int lr4 = (lane >> 4) * 4;
#pragma unroll
  for (int mi = 0; mi < 4; mi++)
#pragma unroll
    for (int r = 0; r < 4; r++) {
      int gm = wm + mi * 16 + lr4 + r;
#pragma unroll
      for (int ni = 0; ni < 4; ni++)
        Pb[gm * 128 + wn + ni * 16 + lc] = acc[mi][ni][r];
    }
}

// Sum the 8 split partials of tile t (batch bz), convert to bf16, write the
// tile and (for off-diagonal tiles) its mirror via an LDS transpose.
__global__ __launch_bounds__(256)
void reduce_xxt(const float* __restrict__ P, u16* __restrict__ G) {
  __shared__ u16 tl[128][130];
  const int t = blockIdx.x, bz = blockIdx.y;
  int by, bx;
  tile_decode(t, by, bx);
  const int m0 = by * 128, n0 = bx * 128;
  u16* Gb = G + (long)bz * 512 * 512;
  for (int e = threadIdx.x; e < 4096; e += 256) {
    const int idx = e * 4;
    const int m = idx >> 7, n = idx & 127;
    f32x4 s = {0.f, 0.f, 0.f, 0.f};
#pragma unroll
    for (int sp = 0; sp < 8; sp++) {
      f32x4 v = *(const f32x4*)&P[(((long)sp * 8 + bz) * 10 + t) * 16384 + idx];
      s.x += v.x; s.y += v.y; s.z += v.z; s.w += v.w;
    }
    us4 o = {f2b(s.x), f2b(s.y), f2b(s.z), f2b(s.w)};
    *(us4*)&Gb[(long)(m0 + m) * 512 + n0 + n] = o;
    tl[m][n] = o[0]; tl[m][n + 1] = o[1]; tl[m][n + 2] = o[2]; tl[m][n + 3] = o[3];
  }
  if (m0 == n0) return;
  __syncthreads();
  for (int e = threadIdx.x; e < 4096; e += 256) {
    const int idx = e * 4;
    const int nr = idx >> 7, mc = idx & 127;
    us4 o = {tl[mc][nr], tl[mc + 1][nr], tl[mc + 2][nr], tl[mc + 3][nr]};
    *(us4*)&Gb[(long)(n0 + nr) * 512 + m0 + mc] = o;
  }
}

// out[b][o][n] = sum_c M[b][o][c] * X[b][c][n] + bias[b][o]  (NN GEMM)
// A staged via global_load_lds (source-swizzled); B (X, n-contiguous)
// staged via global_load_lds directly into the [nb][s][4][16] subtile
// layout (dest byte = c*4096 + tid*16 decomposes as s=(tid>>3)&7,
// r=(tid>>1)&3, h=tid&1, nb=c*4+(tid>>6)); fragments via ds_read_b64_tr_b16.
__global__ __launch_bounds__(256)
void gemm_nn_out(const u16* __restrict__ A, const u16* __restrict__ B,
                 const float* __restrict__ bias, void* __restrict__ Dout,
                 const int* __restrict__ flag) {
  __shared__ __align__(16)  u16 As[128 * 32];
  __shared__ __align__(128) u16 Bs[32 * 128];  // subtiled, 8KB
  const int f = *flag;
  const int bz = blockIdx.z;
  const u16* Ab = A + (long)bz * 512 * 512;
  const u16* Bb = B + (long)bz * 512 * 9216;
  const float* cb = bias + bz * 512;
  const int tid  = threadIdx.x;
  const int lane = tid & 63;
  const int wave = tid >> 6;
  const int wm = (wave >> 1) * 64, wn = (wave & 1) * 64;
  const int m0 = blockIdx.y * 128, n0 = blockIdx.x * 128;
  const int srow = tid >> 2;
  const int ss   = tid & 3;
  const int sco  = (ss ^ ((srow >> 1) & 3)) * 8;
  const int lr = lane & 15;
  const int rsw = (((lane >> 4) ^ ((lr >> 1) & 3)) * 8);
  char* asb = (char*)As + wave * 1024;
  char* bsb = (char*)Bs + wave * 1024;
  // B staging lane decomposition
  const int bs_k = ((tid >> 3) & 7) * 4 + ((tid >> 1) & 3);  // k in 0..31
  const int bs_n = (tid >> 6) * 16 + (tid & 1) * 8;          // n in 0..63
  // tr_read per-lane byte address (fragment ni adds ni*1024):
  const unsigned bsBase = (unsigned)(size_t)(&Bs[0]);
  const unsigned trA = bsBase + (unsigned)((wn >> 4) * 1024 +
                       (lane >> 4) * 256 + (lane & 15) * 8);

  floatx4 acc[4][4];
#pragma unroll
  for (int i = 0; i < 4; i++)
#pragma unroll
    for (int j = 0; j < 4; j++) acc[i][j] = (floatx4){0.f, 0.f, 0.f, 0.f};

  for (int k0 = 0; k0 < 512; k0 += 32) {
    __syncthreads();
    gl_lds16(&Ab[(long)(m0 + srow) * 512 + k0 + sco], asb);
    gl_lds16(&Ab[(long)(m0 + 64 + srow) * 512 + k0 + sco], asb + 4096);
    const u16* bp = &Bb[(long)(k0 + bs_k) * 9216 + n0 + bs_n];
    gl_lds16(bp, bsb);             // nb = tid>>6     (n 0..63)
    gl_lds16(bp + 64, bsb + 4096); // nb = 4+(tid>>6) (n 64..127)
    __syncthreads();
    bf16x8 af[4];
#pragma unroll
    for (int i = 0; i < 4; i++)
      af[i] = *(bf16x8*)&As[(wm + i * 16 + lr) * 32 + rsw];
    u64 blo[4], bhi[4];
#pragma unroll
    for (int ni = 0; ni < 4; ni++) {
      unsigned a = trA + ni * 1024;
      asm volatile("ds_read_b64_tr_b16 %0, %1" : "=v"(blo[ni]) : "v"(a));
      asm volatile("ds_read_b64_tr_b16 %0, %1 offset:128" : "=v"(bhi[ni]) : "v"(a));
    }
    asm volatile("s_waitcnt lgkmcnt(0)" ::: "memory");
    __builtin_amdgcn_sched_barrier(0);
    bf16x8 bfr[4];
#pragma unroll
    for (int ni = 0; ni < 4; ni++) {
      union { u64 q[2]; bf16x8 v; } u;
      u.q[0] = blo[ni]; u.q[1] = bhi[ni];
      bfr[ni] = u.v;
    }
#pragma unroll
    for (int mi = 0; mi < 4; mi++)
#pragma unroll
      for (int ni = 0; ni < 4; ni++)
        acc[mi][ni] = __builtin_amdgcn_mfma_f32_16x16x32_bf16(
            af[mi], bfr[ni], acc[mi][ni], 0, 0, 0);
  }

  const int lc  = lane & 15;
  const int lr4 = (lane >> 4) * 4;
  if (f) {
    float* Db = (float*)Dout + (long)bz * 512 * 9216;
#pragma unroll
    for (int mi = 0; mi < 4; mi++)
#pragma unroll
      for (int r = 0; r < 4; r++) {
        int gm = m0 + wm + mi * 16 + lr4 + r;
        float bv = cb[gm];
#pragma unroll
        for (int ni = 0; ni < 4; ni++)
          Db[(long)gm * 9216 + n0 + wn + ni * 16 + lc] = acc[mi][ni][r] + bv;
      }
  } else {
    u16* Db = (u16*)Dout + (long)bz * 512 * 9216;
#pragma unroll
    for (int mi = 0; mi < 4; mi++)
#pragma unroll
      for (int r = 0; r < 4; r++) {
        int gm = m0 + wm + mi * 16 + lr4 + r;
        float bv = cb[gm];
#pragma unroll
        for (int ni = 0; ni < 4; ni++)
          Db[(long)gm * 9216 + n0 + wn + ni * 16 + lc] = f2b(acc[mi][ni][r] + bv);
      }
  }
}

// r[b][c] = sum_n x[b][c][n]. One wave per row.
__global__ __launch_bounds__(256)
void rowsum(const u16* __restrict__ x, float* __restrict__ r) {
  const int row  = blockIdx.x * 4 + (threadIdx.x >> 6);
  const int lane = threadIdx.x & 63;
  const u16* p = x + (long)row * 9216;
  float s = 0.f;
#pragma unroll
  for (int t = 0; t < 18; t++) {
    us8 v = *(const us8*)&p[t * 512 + lane * 8];
#pragma unroll
    for (int e = 0; e < 8; e++) s += b2f(v[e]);
  }
#pragma unroll
  for (int o = 32; o; o >>= 1) s += __shfl_xor(s, o, 64);
  if (lane == 0) r[row] = s;
}

// u[b][i] = Wq[i,:].r[b,:] ; w[b][i] = Wk[i,:].r[b,:]
__global__ __launch_bounds__(256)
void matvec_uw(const u16* __restrict__ w_qkv, const float* __restrict__ r,
               float* __restrict__ u, float* __restrict__ w) {
  const int g = blockIdx.x * 256 + threadIdx.x;  // 0..8191
  const int b = g >> 10;
  const int s = (g >> 9) & 1;
  const int i = g & 511;
  const u16* Wrow = w_qkv + (long)(s * 512 + i) * 512;
  const float* rb = r + b * 512;
  float acc = 0.f;
  for (int c = 0; c < 512; c++) acc += b2f(Wrow[c]) * rb[c];
  (s ? w : u)[b * 512 + i] = acc;
}

// cv[b][o] = Wp[o,:].y[b,:] + bp[o]
__global__ __launch_bounds__(256)
void cvec(const u16* __restrict__ w_proj, const float* __restrict__ y,
          const u16* __restrict__ b_proj, float* __restrict__ cv) {
  const int g = blockIdx.x * 256 + threadIdx.x;  // 0..4095
  const int b = g >> 9;
  const int o = g & 511;
  const u16* Wrow = w_proj + (long)o * 512;
  const float* yb = y + b * 512;
  float acc = 0.f;
  for (int i = 0; i < 512; i++) acc += b2f(Wrow[i]) * yb[i];
  cv[b * 512 + o] = acc + b2f(b_proj[o]);
}

// Row softmax with rank-1 bias terms. One wave per row i.
__global__ __launch_bounds__(256)
void softmax_rank1(const float* __restrict__ Score, const float* __restrict__ u,
                   const float* __restrict__ w, const u16* __restrict__ b_qkv,
                   u16* __restrict__ PT, float* __restrict__ y) {
  const int row  = blockIdx.x * 4 + (threadIdx.x >> 6);
  const int lane = threadIdx.x & 63;
  const int b = row >> 9, i = row & 511;
  const float scale = 0.04419417382415922f;  // 1/sqrt(512)
  const float* srow = Score + (long)row * 512;
  const float* wb = w + b * 512;
  const float bq_i = b2f(b_qkv[i]);
  const float uu = u[row] + 9216.0f * bq_i;
  float vals[8];
  float mx = -1e30f;
#pragma unroll
  for (int t = 0; t < 8; t++) {
    int j = lane + t * 64;
    float s = srow[j] + uu * b2f(b_qkv[512 + j]) + bq_i * wb[j];
    vals[t] = scale * s;
    mx = fmaxf(mx, vals[t]);
  }
#pragma unroll
  for (int o = 32; o; o >>= 1) mx = fmaxf(mx, __shfl_xor(mx, o, 64));
  float sum = 0.f, ys = 0.f;
#pragma unroll
  for (int t = 0; t < 8; t++) {
    int j = lane + t * 64;
    vals[t] = __expf(vals[t] - mx);
    sum += vals[t];
    ys += vals[t] * b2f(b_qkv[1024 + j]);
  }
#pragma unroll
  for (int o = 32; o; o >>= 1) sum += __shfl_xor(sum, o, 64);
#pragma unroll
  for (int o = 32; o; o >>= 1) ys += __shfl_xor(ys, o, 64);
  const float inv = 1.0f / sum;
#pragma unroll
  for (int t = 0; t < 8; t++) {
    int j = lane + t * 64;
    PT[(long)b * 512 * 512 + (long)j * 512 + i] = f2b(vals[t] * inv);
  }
  if (lane == 0) y[row] = ys * inv;
}

// 512x512 bf16 transpose
__global__ __launch_bounds__(256)
void transpose512(const u16* __restrict__ in, u16* __restrict__ out) {
  __shared__ u16 tile[32][33];
  const int c0 = blockIdx.x * 32, r0 = blockIdx.y * 32;
  const int tx = threadIdx.x, ty = threadIdx.y;
#pragma unroll
  for (int i = 0; i < 32; i += 8)
    tile[ty + i][tx] = in[(long)(r0 + ty + i) * 512 + c0 + tx];
  __syncthreads();
#pragma unroll
  for (int i = 0; i < 32; i += 8)
    out[(long)(c0 + ty + i) * 512 + r0 + tx] = tile[tx][ty + i];
}

extern "C" void kernel_launch(void* const* d_in, const int* in_sizes, int n_in,
                              void* d_out, int out_size, void* d_ws, size_t ws_size,
                              hipStream_t stream) {
  const long CN = 512L * 9216;
  const long SQ = 512L * 512;

  char* ws = (char*)d_ws;
  int*   flag  = (int*)ws;                      ws += 16;
  u16*   Gb    = (u16*)ws;                      ws += 8 * SQ * 2;
  u16*   T1    = (u16*)ws;                      ws += 8 * SQ * 2;
  u16*   PT    = (u16*)ws;                      ws += 8 * SQ * 2;
  u16*   T3    = (u16*)ws;                      ws += 8 * SQ * 2;
  u16*   Mm    = (u16*)ws;                      ws += 8 * SQ * 2;
  float* Score = (float*)ws;                    ws += 8 * SQ * 4;
  u16*   WvT   = (u16*)ws;                      ws += SQ * 2;
  float* r     = (float*)ws;                    ws += 8 * 512 * 4;
  float* u     = (float*)ws;                    ws += 8 * 512 * 4;
  float* w     = (float*)ws;                    ws += 8 * 512 * 4;
  float* y     = (float*)ws;                    ws += 8 * 512 * 4;
  float* cv    = (float*)ws;                    ws += 8 * 512 * 4;
  // canonical bf16 copies of inputs
  u16* xc      = (u16*)ws;                      ws += 8 * CN * 2;     // 75.5 MB
  u16* wqkv_c  = (u16*)ws;                      ws += 1536L * 512 * 2;
  u16* bqkv_c  = (u16*)ws;                      ws += 1536L * 2;
  u16* wproj_c = (u16*)ws;                      ws += 512L * 512 * 2;
  u16* bproj_c = (u16*)ws;                      ws += 512L * 2;

  char* mark1 = ws;
  // split-K fp32 partials: 8 splits x 8 batches x 10 tiles x 128x128 fp32
  float* Psk  = (float*)ws;                     ws += 8L * 8 * 10 * 16384 * 4;

  const bool full  = ((size_t)(mark1 - (char*)d_ws) <= ws_size);
  const bool full2 = ((size_t)(ws    - (char*)d_ws) <= ws_size);

  if (full) {
    detect_dtype<<<1, 256, 0, stream>>>((const u16*)d_in[0], flag, -1);
    convert_bf16<<<18432, 256, 0, stream>>>(d_in[0], xc,      8 * CN,      flag);
    convert_bf16<<<384,   256, 0, stream>>>(d_in[1], wqkv_c,  1536L * 512, flag);
    convert_bf16<<<1,     256, 0, stream>>>(d_in[2], bqkv_c,  1536,        flag);
    convert_bf16<<<128,   256, 0, stream>>>(d_in[3], wproj_c, 512L * 512,  flag);
    convert_bf16<<<1,     256, 0, stream>>>(d_in[4], bproj_c, 512,         flag);
  } else {
    // not enough scratch for copies: assume bf16 inputs, use them directly
    detect_dtype<<<1, 256, 0, stream>>>((const u16*)d_in[0], flag, 0);
    xc      = (u16*)d_in[0];
    wqkv_c  = (u16*)d_in[1];
    bqkv_c  = (u16*)d_in[2];
    wproj_c = (u16*)d_in[3];
    bproj_c = (u16*)d_in[4];
  }

  const u16* Wq = wqkv_c;
  const u16* Wk = wqkv_c + 512 * 512;
  const u16* Wv = wqkv_c + 1024 * 512;

  // 1) G[b] = X X^T (bf16, symmetric)
  if (full2) {
    gemm_xxt_splitk<<<dim3(10, 1, 64), 256, 0, stream>>>(xc, Psk);
    reduce_xxt<<<dim3(10, 8), 256, 0, stream>>>(Psk, Gb);
  } else {
    gemm_nt<u16><<<dim3(8, 8, 8), 256, 0, stream>>>(
        xc, CN, 9216, xc, CN, 9216, Gb, SQ, 512, 9216);
  }
  // 2) row sums + u,w vectors
  rowsum<<<1024, 256, 0, stream>>>(xc, r);
  matvec_uw<<<32, 256, 0, stream>>>(wqkv_c, r, u, w);
  // 3) T1 = Wq G (G symmetric -> NT with B=G)
  gemm_nt<u16><<<dim3(8, 8, 8), 256, 0, stream>>>(
      Wq, 0, 512, Gb, SQ, 512, T1, SQ, 512, 512);
  // 4) Score = T1 Wk^T
  gemm_nt<float><<<dim3(8, 8, 8), 256, 0, stream>>>(
      T1, SQ, 512, Wk, 0, 512, Score, SQ, 512, 512);
  // 5) softmax rows with rank-1 terms -> PT, y
  softmax_rank1<<<1024, 256, 0, stream>>>(Score, u, w, bqkv_c, PT, y);
  // 6) WvT
  transpose512<<<dim3(16, 16), dim3(32, 8), 0, stream>>>(Wv, WvT);
  // 7) T3 = Wp P  (NT with B=PT)
  gemm_nt<u16><<<dim3(8, 8, 8), 256, 0, stream>>>(
      wproj_c, 0, 512, PT, SQ, 512, T3, SQ, 512, 512);
  // 8) M = T3 Wv  (NT with B=WvT)
  gemm_nt<u16><<<dim3(8, 8, 8), 256, 0, stream>>>(
      T3, SQ, 512, WvT, 0, 512, Mm, SQ, 512, 512);
  // 9) cv = Wp y + bp
  cvec<<<16, 256, 0, stream>>>(wproj_c, y, bproj_c, cv);
  // 10) out = M X + cv  (output dtype per flag)
  gemm_nn_out<<<dim3(72, 4, 8), 256, 0, stream>>>(Mm, xc, cv, d_out, flag);
}

// Round 4
// 504.333 us; speedup vs baseline: 1.5026x; 1.0914x over previous
//
#include <hip/hip_runtime.h>

typedef unsigned short u16;
typedef unsigned long long u64;
typedef __bf16 bf16x8 __attribute__((ext_vector_type(8)));
typedef u16 us8 __attribute__((ext_vector_type(8)));
typedef u16 us4 __attribute__((ext_vector_type(4)));
typedef float floatx4 __attribute__((ext_vector_type(4)));
typedef float f32x4 __attribute__((ext_vector_type(4)));

__device__ inline float b2f(u16 u) {
  union { unsigned u; float f; } x; x.u = ((unsigned)u) << 16; return x.f;
}
__device__ inline u16 f2b(float f) {
  union { float f; unsigned u; } x; x.f = f;
  unsigned r = x.u + 0x7fffu + ((x.u >> 16) & 1u);
  return (u16)(r >> 16);
}

// async global->LDS DMA, 16B per lane. LDS dest = wave-uniform base +
// lane*16 (m104); source is per-lane. Swizzles live on the SOURCE (m173).
__device__ __forceinline__ void gl_lds16(const u16* g, void* l) {
  __builtin_amdgcn_global_load_lds(
      (const __attribute__((address_space(1))) void*)g,
      (__attribute__((address_space(3))) void*)l, 16, 0, 0);
}

// Probe first 4096 u16 words of x. bf16 data: max|v| ~ 5.7. fp32 data read
// as bf16: low mantissa halves are ~uniform u16 -> |v|>1000 w.p. ~0.46 each.
__global__ __launch_bounds__(256)
void detect_dtype(const u16* __restrict__ x, int* __restrict__ flag, int force) {
  __shared__ float sm[4];
  const int t = threadIdx.x;
  float m = 0.f;
  for (int i = t; i < 4096; i += 256) {
    float v = fabsf(b2f(x[i]));
    if (v > m) m = v;  // NaN compares false -> skipped; inf caught
  }
#pragma unroll
  for (int o = 32; o; o >>= 1) m = fmaxf(m, __shfl_xor(m, o, 64));
  if ((t & 63) == 0) sm[t >> 6] = m;
  __syncthreads();
  if (t == 0) {
    float mm = fmaxf(fmaxf(sm[0], sm[1]), fmaxf(sm[2], sm[3]));
    *flag = (force >= 0) ? force : (mm > 1000.0f ? 1 : 0);
  }
}

__global__ __launch_bounds__(256)
void zerof(float* __restrict__ p, int n) {
  int i = blockIdx.x * 256 + threadIdx.x;
  if (i < n) p[i] = 0.f;
}

// Canonicalize an input to bf16: copy (bf16 in) or downconvert (fp32 in).
__global__ __launch_bounds__(256)
void convert_bf16(const void* __restrict__ in, u16* __restrict__ out, long n,
                  const int* __restrict__ flag) {
  const long i = (blockIdx.x * 256L + threadIdx.x) * 8;
  if (i >= n) return;
  if (*flag) {
    const float* p = (const float*)in + i;
    f32x4 a = ((const f32x4*)p)[0];
    f32x4 b = ((const f32x4*)p)[1];
    us8 o;
#pragma unroll
    for (int j = 0; j < 4; j++) { o[j] = f2b(a[j]); o[j + 4] = f2b(b[j]); }
    *(us8*)(out + i) = o;
  } else {
    *(us8*)(out + i) = *((const us8*)in + (i >> 3));
  }
}

// convert x AND accumulate row sums r[b*512+c] (rows are 9216 elems;
// 9216 % 512 == 0 so each wave's 512-elem range is within one row ->
// wave shuffle-reduce + one atomicAdd per wave). r must be pre-zeroed.
__global__ __launch_bounds__(256)
void convert_x_rowsum(const void* __restrict__ in, u16* __restrict__ out,
                      const int* __restrict__ flag, float* __restrict__ r) {
  const long i = (blockIdx.x * 256L + threadIdx.x) * 8;
  us8 o;
  if (*flag) {
    const float* p = (const float*)in + i;
    f32x4 a = ((const f32x4*)p)[0];
    f32x4 b = ((const f32x4*)p)[1];
#pragma unroll
    for (int j = 0; j < 4; j++) { o[j] = f2b(a[j]); o[j + 4] = f2b(b[j]); }
  } else {
    o = *((const us8*)in + (i >> 3));
  }
  *(us8*)(out + i) = o;
  float s = 0.f;
#pragma unroll
  for (int j = 0; j < 8; j++) s += b2f(o[j]);
#pragma unroll
  for (int off = 32; off; off >>= 1) s += __shfl_xor(s, off, 64);
  if ((threadIdx.x & 63) == 0) {
    int row = (int)(i / 9216);
    atomicAdd(&r[row], s);
  }
}

// D[M][N] = A[M][K] . B[N][K]^T ; A,B K-contiguous (NT). 64x64 tile,
// 4 waves of 32x32, 2-phase double-buffered global_load_lds staging,
// source-side XOR swizzle. One barrier per K-step (T3 minimum).
template <typename OutT>
__global__ __launch_bounds__(256)
void gemm_nt(const u16* __restrict__ A, long sA, int lda,
             const u16* __restrict__ B, long sB, int ldb,
             OutT* __restrict__ D, long sD, int ldd, int K) {
  __shared__ __align__(16) u16 As[2][64 * 32];
  __shared__ __align__(16) u16 Bs[2][64 * 32];
  const int bz = blockIdx.z;
  const u16* Ab = A + (long)bz * sA;
  const u16* Bb = B + (long)bz * sB;
  OutT* Db = D + (long)bz * sD;
  const int tid  = threadIdx.x;
  const int lane = tid & 63;
  const int wave = tid >> 6;
  const int wm = (wave >> 1) * 32, wn = (wave & 1) * 32;
  const int m0 = blockIdx.y * 64, n0 = blockIdx.x * 64;
  const int srow = tid >> 2;
  const int ss   = tid & 3;
  const int sco  = (ss ^ ((srow >> 1) & 3)) * 8;  // swizzled SOURCE slot
  const int lr = lane & 15;
  const int rsw = (((lane >> 4) ^ ((lr >> 1) & 3)) * 8);

  floatx4 acc[2][2];
#pragma unroll
  for (int i = 0; i < 2; i++)
#pragma unroll
    for (int j = 0; j < 2; j++) acc[i][j] = (floatx4){0.f, 0.f, 0.f, 0.f};

  const int nt = K >> 5;
  auto stage = [&](int buf, int k0) {
    gl_lds16(&Ab[(long)(m0 + srow) * lda + k0 + sco], (char*)As[buf] + wave * 1024);
    gl_lds16(&Bb[(long)(n0 + srow) * ldb + k0 + sco], (char*)Bs[buf] + wave * 1024);
  };
  stage(0, 0);
  __syncthreads();
  for (int t = 0; t < nt; t++) {
    const int cur = t & 1;
    if (t + 1 < nt) stage(cur ^ 1, (t + 1) << 5);
    bf16x8 af[2], bfr[2];
#pragma unroll
    for (int i = 0; i < 2; i++)
      af[i] = *(bf16x8*)&As[cur][(wm + i * 16 + lr) * 32 + rsw];
#pragma unroll
    for (int i = 0; i < 2; i++)
      bfr[i] = *(bf16x8*)&Bs[cur][(wn + i * 16 + lr) * 32 + rsw];
#pragma unroll
    for (int mi = 0; mi < 2; mi++)
#pragma unroll
      for (int ni = 0; ni < 2; ni++)
        acc[mi][ni] = __builtin_amdgcn_mfma_f32_16x16x32_bf16(
            af[mi], bfr[ni], acc[mi][ni], 0, 0, 0);
    __syncthreads();  // waits vmcnt(0): next tile resident; lgkm: reads done
  }

  // C/D layout (m89-verified): col = lane&15, row = (lane>>4)*4 + reg
  const int lc  = lane & 15;
  const int lr4 = (lane >> 4) * 4;
#pragma unroll
  for (int mi = 0; mi < 2; mi++) {
#pragma unroll
    for (int r = 0; r < 4; r++) {
      int gm = m0 + wm + mi * 16 + lr4 + r;
#pragma unroll
      for (int ni = 0; ni < 2; ni++) {
        int gn = n0 + wn + ni * 16 + lc;
        float v = acc[mi][ni][r];
        if constexpr (sizeof(OutT) == 4) Db[(long)gm * ldd + gn] = v;
        else                             Db[(long)gm * ldd + gn] = f2b(v);
      }
    }
  }
}

// ---- split-K symmetric XX^T --------------------------------------------
__device__ inline void tile_decode(int t, int& by, int& bx) {
  by = (int)((sqrtf((float)(8 * t + 1)) - 1.0f) * 0.5f);
  bx = t - (by * (by + 1)) / 2;
}

__global__ __launch_bounds__(256)
void gemm_xxt_splitk(const u16* __restrict__ X, float* __restrict__ P) {
  __shared__ __align__(16) u16 As[2][128 * 32];
  __shared__ __align__(16) u16 Bs[2][128 * 32];
  const int t  = blockIdx.x;        // 0..9
  const int bz = blockIdx.z >> 3;   // batch
  const int sp = blockIdx.z & 7;    // k-split
  int by, bx;
  tile_decode(t, by, bx);
  const int m0 = by * 128, n0 = bx * 128;
  const u16* Xb = X + (long)bz * 512 * 9216;
  const int tid  = threadIdx.x;
  const int lane = tid & 63;
  const int wave = tid >> 6;
  const int wm = (wave >> 1) * 64, wn = (wave & 1) * 64;
  const int srow = tid >> 2;
  const int ss   = tid & 3;
  const int sco  = (ss ^ ((srow >> 1) & 3)) * 8;
  const int lr = lane & 15;
  const int rsw = (((lane >> 4) ^ ((lr >> 1) & 3)) * 8);

  floatx4 acc[4][4];
#pragma unroll
  for (int i = 0; i < 4; i++)
#pragma unroll
    for (int j = 0; j < 4; j++) acc[i][j] = (floatx4){0.f, 0.f, 0.f, 0.f};

  const int k0beg = sp * 1152;
  auto stage = [&](int buf, int k0) {
    gl_lds16(&Xb[(long)(m0 + srow) * 9216 + k0 + sco], (char*)As[buf] + wave * 1024);
    gl_lds16(&Xb[(long)(m0 + 64 + srow) * 9216 + k0 + sco], (char*)As[buf] + 4096 + wave * 1024);
    gl_lds16(&Xb[(long)(n0 + srow) * 9216 + k0 + sco], (char*)Bs[buf] + wave * 1024);
    gl_lds16(&Xb[(long)(n0 + 64 + srow) * 9216 + k0 + sco], (char*)Bs[buf] + 4096 + wave * 1024);
  };
  stage(0, k0beg);
  __syncthreads();
  for (int tt = 0; tt < 36; tt++) {
    const int cur = tt & 1;
    if (tt + 1 < 36) stage(cur ^ 1, k0beg + ((tt + 1) << 5));
    bf16x8 af[4], bfr[4];
#pragma unroll
    for (int i = 0; i < 4; i++)
      af[i] = *(bf16x8*)&As[cur][(wm + i * 16 + lr) * 32 + rsw];
#pragma unroll
    for (int i = 0; i < 4; i++)
      bfr[i] = *(bf16x8*)&Bs[cur][(wn + i * 16 + lr) * 32 + rsw];
#pragma unroll
    for (int mi = 0; mi < 4; mi++)
#pragma unroll
      for (int ni = 0; ni < 4; ni++)
        acc[mi][ni] = __builtin_amdgcn_mfma_f32_16x16x32_bf16(
            af[mi], bfr[ni], acc[mi][ni], 0, 0, 0);
    __syncthreads();
  }

  float* Pb = P + ((long)(sp * 8 + bz) * 10 + t) * 16384;
  const int lc  = lane & 15;
  const int lr4 = (lane >> 4) * 4;
#pragma unroll
  for (int mi = 0; mi < 4; mi++)
#pragma unroll
    for (int r = 0; r < 4; r++) {
      int gm = wm + mi * 16 + lr4 + r;
#pragma unroll
      for (int ni = 0; ni < 4; ni++)
        Pb[gm * 128 + wn + ni * 16 + lc] = acc[mi][ni][r];
    }
}

// Sum the 8 split partials of tile t (batch bz), convert to bf16, write the
// tile and (for off-diagonal tiles) its mirror via an LDS transpose.
__global__ __launch_bounds__(256)
void reduce_xxt(const float* __restrict__ P, u16* __restrict__ G) {
  __shared__ u16 tl[128][130];
  const int t = blockIdx.x, bz = blockIdx.y;
  int by, bx;
  tile_decode(t, by, bx);
  const int m0 = by * 128, n0 = bx * 128;
  u16* Gb = G + (long)bz * 512 * 512;
  for (int e = threadIdx.x; e < 4096; e += 256) {
    const int idx = e * 4;
    const int m = idx >> 7, n = idx & 127;
    f32x4 s = {0.f, 0.f, 0.f, 0.f};
#pragma unroll
    for (int sp = 0; sp < 8; sp++) {
      f32x4 v = *(const f32x4*)&P[(((long)sp * 8 + bz) * 10 + t) * 16384 + idx];
      s.x += v.x; s.y += v.y; s.z += v.z; s.w += v.w;
    }
    us4 o = {f2b(s.x), f2b(s.y), f2b(s.z), f2b(s.w)};
    *(us4*)&Gb[(long)(m0 + m) * 512 + n0 + n] = o;
    tl[m][n] = o[0]; tl[m][n + 1] = o[1]; tl[m][n + 2] = o[2]; tl[m][n + 3] = o[3];
  }
  if (m0 == n0) return;
  __syncthreads();
  for (int e = threadIdx.x; e < 4096; e += 256) {
    const int idx = e * 4;
    const int nr = idx >> 7, mc = idx & 127;
    us4 o = {tl[mc][nr], tl[mc + 1][nr], tl[mc + 2][nr], tl[mc + 3][nr]};
    *(us4*)&Gb[(long)(n0 + nr) * 512 + m0 + mc] = o;
  }
}

// out[b][o][n] = sum_c M[b][o][c] * X[b][c][n] + bias[b][o]  (NN GEMM)
// 2-phase double-buffered. A via gl_lds (source-swizzled); B (X) via gl_lds
// into [nb][s][4][16] subtile layout; fragments via ds_read_b64_tr_b16.
__global__ __launch_bounds__(256)
void gemm_nn_out(const u16* __restrict__ A, const u16* __restrict__ B,
                 const float* __restrict__ bias, void* __restrict__ Dout,
                 const int* __restrict__ flag) {
  __shared__ __align__(16)  u16 As[2][128 * 32];
  __shared__ __align__(128) u16 Bs[2][32 * 128];
  const int f = *flag;
  const int bz = blockIdx.z;
  const u16* Ab = A + (long)bz * 512 * 512;
  const u16* Bb = B + (long)bz * 512 * 9216;
  const float* cb = bias + bz * 512;
  const int tid  = threadIdx.x;
  const int lane = tid & 63;
  const int wave = tid >> 6;
  const int wm = (wave >> 1) * 64, wn = (wave & 1) * 64;
  const int m0 = blockIdx.y * 128, n0 = blockIdx.x * 128;
  const int srow = tid >> 2;
  const int ss   = tid & 3;
  const int sco  = (ss ^ ((srow >> 1) & 3)) * 8;
  const int lr = lane & 15;
  const int rsw = (((lane >> 4) ^ ((lr >> 1) & 3)) * 8);
  // B staging lane decomposition
  const int bs_k = ((tid >> 3) & 7) * 4 + ((tid >> 1) & 3);  // k in 0..31
  const int bs_n = (tid >> 6) * 16 + (tid & 1) * 8;          // n in 0..63
  // tr_read per-lane byte address (fragment ni adds ni*1024, buf adds 8192):
  const unsigned bsBase = (unsigned)(size_t)(&Bs[0][0]);
  const unsigned trA = bsBase + (unsigned)((wn >> 4) * 1024 +
                       (lane >> 4) * 256 + (lane & 15) * 8);

  floatx4 acc[4][4];
#pragma unroll
  for (int i = 0; i < 4; i++)
#pragma unroll
    for (int j = 0; j < 4; j++) acc[i][j] = (floatx4){0.f, 0.f, 0.f, 0.f};

  auto stage = [&](int buf, int k0) {
    gl_lds16(&Ab[(long)(m0 + srow) * 512 + k0 + sco], (char*)As[buf] + wave * 1024);
    gl_lds16(&Ab[(long)(m0 + 64 + srow) * 512 + k0 + sco], (char*)As[buf] + 4096 + wave * 1024);
    const u16* bp = &Bb[(long)(k0 + bs_k) * 9216 + n0 + bs_n];
    gl_lds16(bp, (char*)Bs[buf] + wave * 1024);
    gl_lds16(bp + 64, (char*)Bs[buf] + 4096 + wave * 1024);
  };
  stage(0, 0);
  __syncthreads();
  for (int t = 0; t < 16; t++) {
    const int cur = t & 1;
    if (t + 1 < 16) stage(cur ^ 1, (t + 1) << 5);
    bf16x8 af[4];
#pragma unroll
    for (int i = 0; i < 4; i++)
      af[i] = *(bf16x8*)&As[cur][(wm + i * 16 + lr) * 32 + rsw];
    u64 blo[4], bhi[4];
#pragma unroll
    for (int ni = 0; ni < 4; ni++) {
      unsigned a = trA + cur * 8192 + ni * 1024;
      asm volatile("ds_read_b64_tr_b16 %0, %1" : "=v"(blo[ni]) : "v"(a));
      asm volatile("ds_read_b64_tr_b16 %0, %1 offset:128" : "=v"(bhi[ni]) : "v"(a));
    }
    asm volatile("s_waitcnt lgkmcnt(0)" ::: "memory");
    __builtin_amdgcn_sched_barrier(0);
    bf16x8 bfr[4];
#pragma unroll
    for (int ni = 0; ni < 4; ni++) {
      union { u64 q[2]; bf16x8 v; } u;
      u.q[0] = blo[ni]; u.q[1] = bhi[ni];
      bfr[ni] = u.v;
    }
#pragma unroll
    for (int mi = 0; mi < 4; mi++)
#pragma unroll
      for (int ni = 0; ni < 4; ni++)
        acc[mi][ni] = __builtin_amdgcn_mfma_f32_16x16x32_bf16(
            af[mi], bfr[ni], acc[mi][ni], 0, 0, 0);
    __syncthreads();
  }

  const int lc  = lane & 15;
  const int lr4 = (lane >> 4) * 4;
  if (f) {
    float* Db = (float*)Dout + (long)bz * 512 * 9216;
#pragma unroll
    for (int mi = 0; mi < 4; mi++)
#pragma unroll
      for (int r = 0; r < 4; r++) {
        int gm = m0 + wm + mi * 16 + lr4 + r;
        float bv = cb[gm];
#pragma unroll
        for (int ni = 0; ni < 4; ni++)
          Db[(long)gm * 9216 + n0 + wn + ni * 16 + lc] = acc[mi][ni][r] + bv;
      }
  } else {
    u16* Db = (u16*)Dout + (long)bz * 512 * 9216;
#pragma unroll
    for (int mi = 0; mi < 4; mi++)
#pragma unroll
      for (int r = 0; r < 4; r++) {
        int gm = m0 + wm + mi * 16 + lr4 + r;
        float bv = cb[gm];
#pragma unroll
        for (int ni = 0; ni < 4; ni++)
          Db[(long)gm * 9216 + n0 + wn + ni * 16 + lc] = f2b(acc[mi][ni][r] + bv);
      }
  }
}

// r[b][c] = sum_n x[b][c][n]. One wave per row. (fallback path only)
__global__ __launch_bounds__(256)
void rowsum(const u16* __restrict__ x, float* __restrict__ r) {
  const int row  = blockIdx.x * 4 + (threadIdx.x >> 6);
  const int lane = threadIdx.x & 63;
  const u16* p = x + (long)row * 9216;
  float s = 0.f;
#pragma unroll
  for (int t = 0; t < 18; t++) {
    us8 v = *(const us8*)&p[t * 512 + lane * 8];
#pragma unroll
    for (int e = 0; e < 8; e++) s += b2f(v[e]);
  }
#pragma unroll
  for (int o = 32; o; o >>= 1) s += __shfl_xor(s, o, 64);
  if (lane == 0) r[row] = s;
}

// u[b][i] = Wq[i,:].r[b,:] ; w[b][i] = Wk[i,:].r[b,:]  (one WAVE per output)
__global__ __launch_bounds__(256)
void matvec_uw(const u16* __restrict__ w_qkv, const float* __restrict__ r,
               float* __restrict__ u, float* __restrict__ w) {
  const int g = blockIdx.x * 4 + (threadIdx.x >> 6);  // 0..8191
  const int lane = threadIdx.x & 63;
  const int b = g >> 10;
  const int s = (g >> 9) & 1;
  const int i = g & 511;
  const u16* Wrow = w_qkv + (long)(s * 512 + i) * 512;
  const float* rb = r + b * 512;
  us8 wv = *(const us8*)&Wrow[lane * 8];
  f32x4 r0 = *(const f32x4*)&rb[lane * 8];
  f32x4 r1 = *(const f32x4*)&rb[lane * 8 + 4];
  float acc = b2f(wv[0]) * r0.x + b2f(wv[1]) * r0.y + b2f(wv[2]) * r0.z +
              b2f(wv[3]) * r0.w + b2f(wv[4]) * r1.x + b2f(wv[5]) * r1.y +
              b2f(wv[6]) * r1.z + b2f(wv[7]) * r1.w;
#pragma unroll
  for (int o = 32; o; o >>= 1) acc += __shfl_xor(acc, o, 64);
  if (lane == 0) (s ? w : u)[b * 512 + i] = acc;
}

// cv[b][o] = Wp[o,:].y[b,:] + bp[o]  (one WAVE per output)
__global__ __launch_bounds__(256)
void cvec(const u16* __restrict__ w_proj, const float* __restrict__ y,
          const u16* __restrict__ b_proj, float* __restrict__ cv) {
  const int g = blockIdx.x * 4 + (threadIdx.x >> 6);  // 0..4095
  const int lane = threadIdx.x & 63;
  const int b = g >> 9;
  const int o = g & 511;
  const u16* Wrow = w_proj + (long)o * 512;
  const float* yb = y + b * 512;
  us8 wv = *(const us8*)&Wrow[lane * 8];
  f32x4 y0 = *(const f32x4*)&yb[lane * 8];
  f32x4 y1 = *(const f32x4*)&yb[lane * 8 + 4];
  float acc = b2f(wv[0]) * y0.x + b2f(wv[1]) * y0.y + b2f(wv[2]) * y0.z +
              b2f(wv[3]) * y0.w + b2f(wv[4]) * y1.x + b2f(wv[5]) * y1.y +
              b2f(wv[6]) * y1.z + b2f(wv[7]) * y1.w;
#pragma unroll
  for (int off = 32; off; off >>= 1) acc += __shfl_xor(acc, off, 64);
  if (lane == 0) cv[b * 512 + o] = acc + b2f(b_proj[o]);
}

// Row softmax with rank-1 bias terms. One wave per row i.
__global__ __launch_bounds__(256)
void softmax_rank1(const float* __restrict__ Score, const float* __restrict__ u,
                   const float* __restrict__ w, const u16* __restrict__ b_qkv,
                   u16* __restrict__ PT, float* __restrict__ y) {
  const int row  = blockIdx.x * 4 + (threadIdx.x >> 6);
  const int lane = threadIdx.x & 63;
  const int b = row >> 9, i = row & 511;
  const float scale = 0.04419417382415922f;  // 1/sqrt(512)
  const float* srow = Score + (long)row * 512;
  const float* wb = w + b * 512;
  const float bq_i = b2f(b_qkv[i]);
  const float uu = u[row] + 9216.0f * bq_i;
  float vals[8];
  float mx = -1e30f;
#pragma unroll
  for (int t = 0; t < 8; t++) {
    int j = lane + t * 64;
    float s = srow[j] + uu * b2f(b_qkv[512 + j]) + bq_i * wb[j];
    vals[t] = scale * s;
    mx = fmaxf(mx, vals[t]);
  }
#pragma unroll
  for (int o = 32; o; o >>= 1) mx = fmaxf(mx, __shfl_xor(mx, o, 64));
  float sum = 0.f, ys = 0.f;
#pragma unroll
  for (int t = 0; t < 8; t++) {
    int j = lane + t * 64;
    vals[t] = __expf(vals[t] - mx);
    sum += vals[t];
    ys += vals[t] * b2f(b_qkv[1024 + j]);
  }
#pragma unroll
  for (int o = 32; o; o >>= 1) sum += __shfl_xor(sum, o, 64);
#pragma unroll
  for (int o = 32; o; o >>= 1) ys += __shfl_xor(ys, o, 64);
  const float inv = 1.0f / sum;
#pragma unroll
  for (int t = 0; t < 8; t++) {
    int j = lane + t * 64;
    PT[(long)b * 512 * 512 + (long)j * 512 + i] = f2b(vals[t] * inv);
  }
  if (lane == 0) y[row] = ys * inv;
}

// 512x512 bf16 transpose
__global__ __launch_bounds__(256)
void transpose512(const u16* __restrict__ in, u16* __restrict__ out) {
  __shared__ u16 tile[32][33];
  const int c0 = blockIdx.x * 32, r0 = blockIdx.y * 32;
  const int tx = threadIdx.x, ty = threadIdx.y;
#pragma unroll
  for (int i = 0; i < 32; i += 8)
    tile[ty + i][tx] = in[(long)(r0 + ty + i) * 512 + c0 + tx];
  __syncthreads();
#pragma unroll
  for (int i = 0; i < 32; i += 8)
    out[(long)(c0 + ty + i) * 512 + r0 + tx] = tile[tx][ty + i];
}

extern "C" void kernel_launch(void* const* d_in, const int* in_sizes, int n_in,
                              void* d_out, int out_size, void* d_ws, size_t ws_size,
                              hipStream_t stream) {
  const long CN = 512L * 9216;
  const long SQ = 512L * 512;

  char* ws = (char*)d_ws;
  int*   flag  = (int*)ws;                      ws += 16;
  u16*   Gb    = (u16*)ws;                      ws += 8 * SQ * 2;
  u16*   T1    = (u16*)ws;                      ws += 8 * SQ * 2;
  u16*   PT    = (u16*)ws;                      ws += 8 * SQ * 2;
  u16*   T3    = (u16*)ws;                      ws += 8 * SQ * 2;
  u16*   Mm    = (u16*)ws;                      ws += 8 * SQ * 2;
  float* Score = (float*)ws;                    ws += 8 * SQ * 4;
  u16*   WvT   = (u16*)ws;                      ws += SQ * 2;
  float* r     = (float*)ws;                    ws += 8 * 512 * 4;
  float* u     = (float*)ws;                    ws += 8 * 512 * 4;
  float* w     = (float*)ws;                    ws += 8 * 512 * 4;
  float* y     = (float*)ws;                    ws += 8 * 512 * 4;
  float* cv    = (float*)ws;                    ws += 8 * 512 * 4;
  // canonical bf16 copies of inputs
  u16* xc      = (u16*)ws;                      ws += 8 * CN * 2;     // 75.5 MB
  u16* wqkv_c  = (u16*)ws;                      ws += 1536L * 512 * 2;
  u16* bqkv_c  = (u16*)ws;                      ws += 1536L * 2;
  u16* wproj_c = (u16*)ws;                      ws += 512L * 512 * 2;
  u16* bproj_c = (u16*)ws;                      ws += 512L * 2;

  char* mark1 = ws;
  // split-K fp32 partials: 8 splits x 8 batches x 10 tiles x 128x128 fp32
  float* Psk  = (float*)ws;                     ws += 8L * 8 * 10 * 16384 * 4;

  const bool full  = ((size_t)(mark1 - (char*)d_ws) <= ws_size);
  const bool full2 = ((size_t)(ws    - (char*)d_ws) <= ws_size);

  if (full) {
    detect_dtype<<<1, 256, 0, stream>>>((const u16*)d_in[0], flag, -1);
    zerof<<<16, 256, 0, stream>>>(r, 4096);
    convert_x_rowsum<<<18432, 256, 0, stream>>>(d_in[0], xc, flag, r);
    convert_bf16<<<384,   256, 0, stream>>>(d_in[1], wqkv_c,  1536L * 512, flag);
    convert_bf16<<<1,     256, 0, stream>>>(d_in[2], bqkv_c,  1536,        flag);
    convert_bf16<<<128,   256, 0, stream>>>(d_in[3], wproj_c, 512L * 512,  flag);
    convert_bf16<<<1,     256, 0, stream>>>(d_in[4], bproj_c, 512,         flag);
  } else {
    // not enough scratch for copies: assume bf16 inputs, use them directly
    detect_dtype<<<1, 256, 0, stream>>>((const u16*)d_in[0], flag, 0);
    xc      = (u16*)d_in[0];
    wqkv_c  = (u16*)d_in[1];
    bqkv_c  = (u16*)d_in[2];
    wproj_c = (u16*)d_in[3];
    bproj_c = (u16*)d_in[4];
    rowsum<<<1024, 256, 0, stream>>>(xc, r);
  }

  const u16* Wq = wqkv_c;
  const u16* Wk = wqkv_c + 512 * 512;
  const u16* Wv = wqkv_c + 1024 * 512;

  // 1) G[b] = X X^T (bf16, symmetric)
  if (full2) {
    gemm_xxt_splitk<<<dim3(10, 1, 64), 256, 0, stream>>>(xc, Psk);
    reduce_xxt<<<dim3(10, 8), 256, 0, stream>>>(Psk, Gb);
  } else {
    gemm_nt<u16><<<dim3(8, 8, 8), 256, 0, stream>>>(
        xc, CN, 9216, xc, CN, 9216, Gb, SQ, 512, 9216);
  }
  // 2) u,w vectors from row sums
  matvec_uw<<<2048, 256, 0, stream>>>(wqkv_c, r, u, w);
  // 3) T1 = Wq G (G symmetric -> NT with B=G)
  gemm_nt<u16><<<dim3(8, 8, 8), 256, 0, stream>>>(
      Wq, 0, 512, Gb, SQ, 512, T1, SQ, 512, 512);
  // 4) Score = T1 Wk^T
  gemm_nt<float><<<dim3(8, 8, 8), 256, 0, stream>>>(
      T1, SQ, 512, Wk, 0, 512, Score, SQ, 512, 512);
  // 5) softmax rows with rank-1 terms -> PT, y
  softmax_rank1<<<1024, 256, 0, stream>>>(Score, u, w, bqkv_c, PT, y);
  // 6) WvT
  transpose512<<<dim3(16, 16), dim3(32, 8), 0, stream>>>(Wv, WvT);
  // 7) T3 = Wp P  (NT with B=PT)
  gemm_nt<u16><<<dim3(8, 8, 8), 256, 0, stream>>>(
      wproj_c, 0, 512, PT, SQ, 512, T3, SQ, 512, 512);
  // 8) M = T3 Wv  (NT with B=WvT)
  gemm_nt<u16><<<dim3(8, 8, 8), 256, 0, stream>>>(
      T3, SQ, 512, WvT, 0, 512, Mm, SQ, 512, 512);
  // 9) cv = Wp y + bp
  cvec<<<1024, 256, 0, stream>>>(wproj_c, y, bproj_c, cv);
  // 10) out = M X + cv  (output dtype per flag)
  gemm_nn_out<<<dim3(72, 4, 8), 256, 0, stream>>>(Mm, xc, cv, d_out, flag);
}